// Round 2
// baseline (447.941 us; speedup 1.0000x reference)
//
#include <hip/hip_runtime.h>
#include <hip/hip_fp16.h>

// Memory_Attention: r = softmax_L(memory @ qs^T) @ qs ; out = (r, memory)
// B=8 L=4096 D=1024 M=512, fp32 in/out.
//
// Round 2: latency-bound fix. Grid 256->512 (TM 64->32) => 2 blocks/CU, 4 waves/SIMD.
// Pre-convert qs to fp16 (qs16) to make score B-frags single 16B loads (ws permitting).
// Runtime ws_size dispatch: BIG (qs16 path) / SMALL (fp32 B loads) / fallback.

#define B_ 8
#define L_ 4096
#define D_ 1024
#define M_ 512

typedef _Float16 halfT;
typedef _Float16 half8 __attribute__((ext_vector_type(8)));
typedef _Float16 half2_t __attribute__((ext_vector_type(2)));
typedef float f32x4 __attribute__((ext_vector_type(4)));

// ---- ws layouts (bytes) ----
// BIG:   qsT(67M) qs16(67M) mem16(1M) rpart(67M) mstat lstat   = 202,506,240
// SMALL: qsT(67M)           mem16(1M) rpart(67M) mstat lstat   = 135,397,376
#define SZ_QST    (8ull*1024*4096*2)
#define SZ_QS16   (8ull*4096*1024*2)
#define SZ_MEM16  (512ull*1024*2)
#define SZ_RPART  (4ull*8*512*1024*4)
#define SZ_STAT   (4ull*8*512*4)
#define WS_BIG    (SZ_QST + SZ_QS16 + SZ_MEM16 + SZ_RPART + 2*SZ_STAT)
#define WS_SMALL  (SZ_QST + SZ_MEM16 + SZ_RPART + 2*SZ_STAT)

__device__ __forceinline__ f32x4 fmax4(f32x4 a, f32x4 b) {
  f32x4 r; r[0]=fmaxf(a[0],b[0]); r[1]=fmaxf(a[1],b[1]);
  r[2]=fmaxf(a[2],b[2]); r[3]=fmaxf(a[3],b[3]); return r;
}
__device__ __forceinline__ f32x4 shfl_xor4(f32x4 v, int m) {
  f32x4 r; r[0]=__shfl_xor(v[0],m); r[1]=__shfl_xor(v[1],m);
  r[2]=__shfl_xor(v[2],m); r[3]=__shfl_xor(v[3],m); return r;
}

// ---------------- prep kernels ----------------
__global__ void prep_mem16(const float* __restrict__ mem, halfT* __restrict__ mem16) {
  int i = blockIdx.x*256 + threadIdx.x;   // 2048*256 = 524288 exact
  mem16[i] = (halfT)mem[i];
}

// One pass over qs: write qs16 [b][l][d] and qsT [b][d][l], both fp16.
__global__ void prep_qs(const float* __restrict__ qs,
                        halfT* __restrict__ qs16, halfT* __restrict__ qsT) {
  __shared__ halfT tile[64][66];
  int b = blockIdx.z, l0 = blockIdx.x*64, d0 = blockIdx.y*64;
  int tid = threadIdx.x;
  const float* src = qs + ((size_t)b*L_ + l0)*D_ + d0;
  halfT* d16 = qs16 + ((size_t)b*L_ + l0)*D_ + d0;
  #pragma unroll
  for (int i = 0; i < 8; ++i) {
    int idx = i*256 + tid;
    int r = idx >> 5, c = (idx & 31)*2;        // r=l row, c=d col (pair)
    float2 v = *(const float2*)&src[(size_t)r*D_ + c];
    half2_t p; p[0] = (halfT)v.x; p[1] = (halfT)v.y;
    *(half2_t*)&tile[r][c] = p;
    *(half2_t*)&d16[(size_t)r*D_ + c] = p;
  }
  __syncthreads();
  halfT* dT = qsT + ((size_t)b*D_ + d0)*L_ + l0;
  #pragma unroll
  for (int i = 0; i < 8; ++i) {
    int idx = i*256 + tid;
    int r = idx >> 5, c = (idx & 31)*2;        // r=d row, c=l col (pair)
    half2_t p; p[0] = tile[c][r]; p[1] = tile[c+1][r];
    *(half2_t*)&dT[(size_t)r*L_ + c] = p;
  }
}

// round-1 transpose-only prep (SMALL path)
__global__ void prep_transpose(const float* __restrict__ qs, halfT* __restrict__ qsT) {
  __shared__ halfT tile[64][66];
  int b = blockIdx.z, l0 = blockIdx.x*64, d0 = blockIdx.y*64;
  int tid = threadIdx.x;
  const float* src = qs + ((size_t)b*L_ + l0)*D_ + d0;
  #pragma unroll
  for (int i = 0; i < 8; ++i) {
    int idx = i*256 + tid;
    int r = idx >> 5, c = (idx & 31)*2;
    float2 v = *(const float2*)&src[(size_t)r*D_ + c];
    half2_t p; p[0] = (halfT)v.x; p[1] = (halfT)v.y;
    *(half2_t*)&tile[r][c] = p;
  }
  __syncthreads();
  halfT* dT = qsT + ((size_t)b*D_ + d0)*L_ + l0;
  #pragma unroll
  for (int i = 0; i < 8; ++i) {
    int idx = i*256 + tid;
    int r = idx >> 5, c = (idx & 31)*2;
    half2_t p; p[0] = tile[c][r]; p[1] = tile[c+1][r];
    *(half2_t*)&dT[(size_t)r*L_ + c] = p;
  }
}

// ---------------- main fused kernel ----------------
// TM=32, chunk=1024 L (4 tiles of 256), 8 waves x 32 l-cols, PV: 8 waves x 128 d.
// grid 512: xcd=wg&7; r=wg>>3; mt=r&15; chunk p=(r>>4)*8+xcd; 16 m-tiles of one
// (b,ls) chunk share an XCD for L2 reuse.
template<bool QS16>
__launch_bounds__(512, 2)
__global__ void flash_main(const float* __restrict__ qs,
                           const halfT* __restrict__ qs16,
                           const halfT* __restrict__ mem16,
                           const halfT* __restrict__ qsT,
                           float* __restrict__ r_part,
                           float* __restrict__ mstat,
                           float* __restrict__ lstat)
{
  int wg  = blockIdx.x;          // 0..511
  int xcd = wg & 7;
  int rr_ = wg >> 3;             // 0..63
  int mt  = rr_ & 15;
  int p   = (rr_ >> 4)*8 + xcd;  // chunk id 0..31
  int b   = p >> 2;
  int ls  = p & 3;

  int m0    = mt*32;
  int lbase = ls*1024;

  int tid = threadIdx.x;
  int w = tid >> 6, lane = tid & 63, lg = lane >> 4, li = lane & 15;

  __shared__ __attribute__((aligned(16))) halfT P_lds[32][272];
  __shared__ __attribute__((aligned(16))) float rowmax_ws[8][32];
  __shared__ __attribute__((aligned(16))) float rowsum_ws[8][32];
  __shared__ __attribute__((aligned(16))) float mnew_lds[32];
  __shared__ __attribute__((aligned(16))) float f_lds[32];
  __shared__ __attribute__((aligned(16))) float mrun_lds[32];
  __shared__ __attribute__((aligned(16))) float lrun_lds[32];

  if (tid < 32) { mrun_lds[tid] = -3.0e38f; lrun_lds[tid] = 0.0f; }
  __syncthreads();

  f32x4 acc[2][8];
  #pragma unroll
  for (int i=0;i<2;++i)
    #pragma unroll
    for (int j=0;j<8;++j) acc[i][j] = (f32x4){0.f,0.f,0.f,0.f};

  const halfT* Abase = mem16 + (size_t)(m0 + li)*D_;

  for (int t = 0; t < 4; ++t) {
    int ltile = lbase + t*256;

    // ---------- scores S[2mf][2lf]; wave cols = w*32 + lf*16 + li ----------
    f32x4 S[2][2];
    #pragma unroll
    for (int i=0;i<2;++i) { S[i][0]=(f32x4){0,0,0,0}; S[i][1]=(f32x4){0,0,0,0}; }
    const halfT* q0h = qs16 + ((size_t)b*L_ + (ltile + w*32 + li))*D_;
    const float* q0f = qs   + ((size_t)b*L_ + (ltile + w*32 + li))*D_;
    #pragma unroll 4
    for (int ks = 0; ks < 32; ++ks) {
      int k = ks*32 + lg*8;
      half8 Af0 = *(const half8*)(Abase + k);
      half8 Af1 = *(const half8*)(Abase + (size_t)16*D_ + k);
      half8 Bf[2];
      if constexpr (QS16) {
        Bf[0] = *(const half8*)(q0h + k);
        Bf[1] = *(const half8*)(q0h + (size_t)16*D_ + k);
      } else {
        #pragma unroll
        for (int lf=0; lf<2; ++lf) {
          const float* qp = q0f + (size_t)lf*16*D_ + k;
          f32x4 x0 = *(const f32x4*)qp;
          f32x4 x1 = *(const f32x4*)(qp + 4);
          #pragma unroll
          for (int j=0;j<4;++j) { Bf[lf][j] = (halfT)x0[j]; Bf[lf][4+j] = (halfT)x1[j]; }
        }
      }
      S[0][0] = __builtin_amdgcn_mfma_f32_16x16x32_f16(Af0, Bf[0], S[0][0], 0,0,0);
      S[1][0] = __builtin_amdgcn_mfma_f32_16x16x32_f16(Af1, Bf[0], S[1][0], 0,0,0);
      S[0][1] = __builtin_amdgcn_mfma_f32_16x16x32_f16(Af0, Bf[1], S[0][1], 0,0,0);
      S[1][1] = __builtin_amdgcn_mfma_f32_16x16x32_f16(Af1, Bf[1], S[1][1], 0,0,0);
    }

    // ---------- wave-partial row max ----------
    #pragma unroll
    for (int mf=0; mf<2; ++mf) {
      f32x4 v = fmax4(S[mf][0], S[mf][1]);
      #pragma unroll
      for (int off=1; off<16; off<<=1) v = fmax4(v, shfl_xor4(v, off));
      if (li == 0) *(f32x4*)&rowmax_ws[w][mf*16 + lg*4] = v;
    }
    __syncthreads();

    if (tid < 32) {
      float mx = rowmax_ws[0][tid];
      #pragma unroll
      for (int s=1;s<8;++s) mx = fmaxf(mx, rowmax_ws[s][tid]);
      float mo = mrun_lds[tid];
      float mn = fmaxf(mo, mx);
      mrun_lds[tid] = mn; mnew_lds[tid] = mn;
      f_lds[tid] = __expf(mo - mn);
    }
    __syncthreads();

    // ---------- P = exp(S - mnew) -> P_lds fp16 ; partial row sums ----------
    #pragma unroll
    for (int mf=0; mf<2; ++mf) {
      f32x4 mn4 = *(const f32x4*)&mnew_lds[mf*16 + lg*4];
      f32x4 sum = (f32x4){0,0,0,0};
      #pragma unroll
      for (int lf=0; lf<2; ++lf) {
        f32x4 pv;
        #pragma unroll
        for (int r=0;r<4;++r) pv[r] = __expf(S[mf][lf][r] - mn4[r]);
        sum += pv;
        int col = w*32 + lf*16 + li;
        #pragma unroll
        for (int r=0;r<4;++r) P_lds[mf*16 + lg*4 + r][col] = (halfT)pv[r];
      }
      #pragma unroll
      for (int off=1; off<16; off<<=1) sum += shfl_xor4(sum, off);
      if (li == 0) *(f32x4*)&rowsum_ws[w][mf*16 + lg*4] = sum;
    }
    __syncthreads();

    if (tid < 32) {
      float ts = 0.f;
      #pragma unroll
      for (int s=0;s<8;++s) ts += rowsum_ws[s][tid];
      lrun_lds[tid] = lrun_lds[tid]*f_lds[tid] + ts;
    }

    // ---------- rescale acc, PV over this tile (K=256) ----------
    #pragma unroll
    for (int mf=0; mf<2; ++mf) {
      f32x4 f4 = *(const f32x4*)&f_lds[mf*16 + lg*4];
      #pragma unroll
      for (int df=0; df<8; ++df) acc[mf][df] *= f4;
    }
    const halfT* Tbase = qsT + ((size_t)b*D_ + (w*128 + li))*L_ + ltile;
    #pragma unroll 2
    for (int ks=0; ks<8; ++ks) {
      int k = ks*32 + lg*8;
      half8 Pf[2];
      Pf[0] = *(const half8*)&P_lds[li][k];
      Pf[1] = *(const half8*)&P_lds[16 + li][k];
      #pragma unroll
      for (int dg=0; dg<2; ++dg) {
        half8 Bt[4];
        #pragma unroll
        for (int dj=0; dj<4; ++dj)
          Bt[dj] = *(const half8*)(Tbase + (size_t)(dg*4+dj)*16*L_ + k);
        #pragma unroll
        for (int dj=0; dj<4; ++dj) {
          acc[0][dg*4+dj] = __builtin_amdgcn_mfma_f32_16x16x32_f16(Pf[0], Bt[dj], acc[0][dg*4+dj], 0,0,0);
          acc[1][dg*4+dj] = __builtin_amdgcn_mfma_f32_16x16x32_f16(Pf[1], Bt[dj], acc[1][dg*4+dj], 0,0,0);
        }
      }
    }
  }

  // ---------- epilogue ----------
  size_t chunk = (size_t)ls*B_ + b;
  #pragma unroll
  for (int mf=0; mf<2; ++mf)
    #pragma unroll
    for (int df=0; df<8; ++df)
      #pragma unroll
      for (int r=0; r<4; ++r) {
        int m = m0 + mf*16 + lg*4 + r;
        int d = w*128 + df*16 + li;
        r_part[(chunk*M_ + m)*D_ + d] = acc[mf][df][r];
      }
  if (tid < 32) {
    mstat[chunk*M_ + m0 + tid] = mrun_lds[tid];
    lstat[chunk*M_ + m0 + tid] = lrun_lds[tid];
  }
}

// ---------------- combine ----------------
__global__ void combine(const float* __restrict__ r_part,
                        const float* __restrict__ mstat,
                        const float* __restrict__ lstat,
                        float* __restrict__ out)
{
  int bm = blockIdx.x;        // b*512+m
  int tid = threadIdx.x;
  float ms[4], wsc[4];
  float Mx = -3.0e38f;
  #pragma unroll
  for (int s=0;s<4;++s) { ms[s] = mstat[(size_t)s*4096 + bm]; Mx = fmaxf(Mx, ms[s]); }
  float Z = 0.f;
  #pragma unroll
  for (int s=0;s<4;++s) { wsc[s] = __expf(ms[s] - Mx); Z += wsc[s]*lstat[(size_t)s*4096 + bm]; }
  float inv = 1.f / Z;
  for (int d = tid; d < D_; d += 256) {
    float v = 0.f;
    #pragma unroll
    for (int s=0;s<4;++s) v += wsc[s]*r_part[((size_t)s*4096 + bm)*D_ + d];
    out[(size_t)bm*D_ + d] = v*inv;
  }
}

// ---------------- fallback (tiny ws): correct, slow fp32 ----------------
__global__ void fallback_kernel(const float* __restrict__ qs,
                                const float* __restrict__ mem,
                                float* __restrict__ out)
{
  __shared__ float w_lds[4][4096];
  __shared__ float mem_s[4][1024];
  __shared__ float redb[256];
  int blk = blockIdx.x;
  int b = blk >> 7;
  int m0 = (blk & 127)*4;
  int tid = threadIdx.x;

  for (int i = tid; i < 4*1024; i += 256)
    mem_s[i>>10][i&1023] = mem[(size_t)(m0 + (i>>10))*D_ + (i&1023)];
  __syncthreads();

  float mx[4] = {-3e38f,-3e38f,-3e38f,-3e38f};
  for (int l = tid; l < L_; l += 256) {
    const float* qp = qs + ((size_t)b*L_ + l)*D_;
    float dot[4] = {0,0,0,0};
    for (int dd = 0; dd < D_; dd += 4) {
      f32x4 qv = *(const f32x4*)(qp + dd);
      #pragma unroll
      for (int mi=0; mi<4; ++mi)
        dot[mi] += qv[0]*mem_s[mi][dd] + qv[1]*mem_s[mi][dd+1]
                 + qv[2]*mem_s[mi][dd+2] + qv[3]*mem_s[mi][dd+3];
    }
    #pragma unroll
    for (int mi=0; mi<4; ++mi) { w_lds[mi][l] = dot[mi]; mx[mi] = fmaxf(mx[mi], dot[mi]); }
  }
  float Mv[4], Zv[4];
  for (int mi=0; mi<4; ++mi) {
    redb[tid] = mx[mi]; __syncthreads();
    for (int s=128; s>0; s>>=1) { if (tid<s) redb[tid]=fmaxf(redb[tid],redb[tid+s]); __syncthreads(); }
    Mv[mi] = redb[0]; __syncthreads();
  }
  float sm[4] = {0,0,0,0};
  for (int l = tid; l < L_; l += 256)
    #pragma unroll
    for (int mi=0; mi<4; ++mi) {
      float wv = __expf(w_lds[mi][l] - Mv[mi]);
      w_lds[mi][l] = wv; sm[mi] += wv;
    }
  for (int mi=0; mi<4; ++mi) {
    redb[tid] = sm[mi]; __syncthreads();
    for (int s=128; s>0; s>>=1) { if (tid<s) redb[tid]+=redb[tid+s]; __syncthreads(); }
    Zv[mi] = redb[0]; __syncthreads();
  }
  int d0 = tid*4;
  f32x4 a[4];
  #pragma unroll
  for (int mi=0;mi<4;++mi) a[mi] = (f32x4){0,0,0,0};
  for (int l = 0; l < L_; ++l) {
    f32x4 qv = *(const f32x4*)(qs + ((size_t)b*L_ + l)*D_ + d0);
    #pragma unroll
    for (int mi=0; mi<4; ++mi) a[mi] += qv * w_lds[mi][l];
  }
  #pragma unroll
  for (int mi=0; mi<4; ++mi) {
    float invz = 1.f/Zv[mi];
    #pragma unroll
    for (int c=0; c<4; ++c)
      out[((size_t)b*M_ + m0 + mi)*D_ + d0 + c] = a[mi][c]*invz;
  }
}

extern "C" void kernel_launch(void* const* d_in, const int* in_sizes, int n_in,
                              void* d_out, int out_size, void* d_ws, size_t ws_size,
                              hipStream_t stream) {
  const float* qs  = (const float*)d_in[0];
  const float* mem = (const float*)d_in[1];
  float* out = (float*)d_out;

  // tuple output: r [8*512*1024] then memory [512*1024]
  hipMemcpyAsync(out + (size_t)B_*M_*D_, mem, (size_t)M_*D_*sizeof(float),
                 hipMemcpyDeviceToDevice, stream);

  if (ws_size >= (size_t)WS_BIG) {
    char* base = (char*)d_ws;
    halfT* qsT    = (halfT*)(base);
    halfT* qs16   = (halfT*)(base + SZ_QST);
    halfT* mem16  = (halfT*)(base + SZ_QST + SZ_QS16);
    float* r_part = (float*)(base + SZ_QST + SZ_QS16 + SZ_MEM16);
    float* mstat  = (float*)(base + SZ_QST + SZ_QS16 + SZ_MEM16 + SZ_RPART);
    float* lstat  = (float*)(base + SZ_QST + SZ_QS16 + SZ_MEM16 + SZ_RPART + SZ_STAT);

    prep_mem16<<<2048, 256, 0, stream>>>(mem, mem16);
    prep_qs<<<dim3(64,16,8), 256, 0, stream>>>(qs, qs16, qsT);
    flash_main<true><<<512, 512, 0, stream>>>(qs, qs16, mem16, qsT, r_part, mstat, lstat);
    combine<<<4096, 256, 0, stream>>>(r_part, mstat, lstat, out);
  } else if (ws_size >= (size_t)WS_SMALL) {
    char* base = (char*)d_ws;
    halfT* qsT    = (halfT*)(base);
    halfT* mem16  = (halfT*)(base + SZ_QST);
    float* r_part = (float*)(base + SZ_QST + SZ_MEM16);
    float* mstat  = (float*)(base + SZ_QST + SZ_MEM16 + SZ_RPART);
    float* lstat  = (float*)(base + SZ_QST + SZ_MEM16 + SZ_RPART + SZ_STAT);

    prep_mem16<<<2048, 256, 0, stream>>>(mem, mem16);
    prep_transpose<<<dim3(64,16,8), 256, 0, stream>>>(qs, qsT);
    flash_main<false><<<512, 512, 0, stream>>>(qs, nullptr, mem16, qsT, r_part, mstat, lstat);
    combine<<<4096, 256, 0, stream>>>(r_part, mstat, lstat, out);
  } else {
    fallback_kernel<<<1024, 256, 0, stream>>>(qs, mem, out);
  }
}

// Round 3
// 221.108 us; speedup vs baseline: 2.0259x; 2.0259x over previous
//
#include <hip/hip_runtime.h>
#include <hip/hip_fp16.h>

// Memory_Attention: r = softmax_L(memory @ qs^T) @ qs ; out = (r, memory)
// B=8 L=4096 D=1024 M=512, fp32 in/out.
//
// Round 3: decomposed pipeline on the proven m97 GEMM template.
//   prep_mem16 / prep_qs : fp32 -> fp16 (qs16 [b][l][d], qsT [b][d][l], mem16)
//   gemm_bt<0>           : S = mem16 @ qs16^T   (per b: M=512,N=4096,K=1024)
//   softmax_rows         : P16 = exp(S - rowmax) fp16, invl = 1/rowsum
//   gemm_bt<1>           : r = (P16 @ qsT^T) * invl  (per b: M=512,N=1024,K=4096)
// gemm_bt: 64x128 tile, BK=64, 4 waves, global_load_lds dwordx4 staging,
// 2-barrier K-loop, linear LDS (m97 structure). XCD-swizzled block order.
// ws known >= 202,506,240 B (round-2 BIG path ran). P16 overlays qs16.

#define B_ 8
#define L_ 4096
#define D_ 1024
#define M_ 512

typedef _Float16 halfT;
typedef _Float16 half8 __attribute__((ext_vector_type(8)));
typedef _Float16 half4_t __attribute__((ext_vector_type(4)));
typedef _Float16 half2_t __attribute__((ext_vector_type(2)));
typedef float f32x4 __attribute__((ext_vector_type(4)));

// ---- ws layout (bytes) ----
#define OFF_QST   0ull
#define SZ_QST    (8ull*1024*4096*2)          // 67,108,864
#define OFF_QS16  (OFF_QST + SZ_QST)
#define SZ_QS16   (8ull*4096*1024*2)          // 67,108,864
#define OFF_MEM16 (OFF_QS16 + SZ_QS16)
#define SZ_MEM16  (512ull*1024*2)             //  1,048,576
#define OFF_S     (OFF_MEM16 + SZ_MEM16)
#define SZ_S      (8ull*512*4096*4)           // 67,108,864
#define OFF_INVL  (OFF_S + SZ_S)
#define SZ_INVL   (8ull*512*4)
#define WS_NEED   (OFF_INVL + SZ_INVL)        // 202,391,552 <= 202,506,240 (known present)
#define OFF_P16   OFF_QS16                    // overlay: qs16 dead after gemm1

__device__ __forceinline__ void gload_lds16(const halfT* g, halfT* l) {
  __builtin_amdgcn_global_load_lds(
      (const __attribute__((address_space(1))) unsigned int*)(const void*)g,
      (__attribute__((address_space(3))) unsigned int*)l, 16, 0, 0);
}

// ---------------- prep kernels ----------------
__global__ void prep_mem16(const float* __restrict__ mem, halfT* __restrict__ mem16) {
  int i = blockIdx.x*256 + threadIdx.x;   // 2048*256 = 524288 exact
  mem16[i] = (halfT)mem[i];
}

// One pass over qs: write qs16 [b][l][d] and qsT [b][d][l], both fp16.
__global__ void prep_qs(const float* __restrict__ qs,
                        halfT* __restrict__ qs16, halfT* __restrict__ qsT) {
  __shared__ halfT tile[64][66];
  int b = blockIdx.z, l0 = blockIdx.x*64, d0 = blockIdx.y*64;
  int tid = threadIdx.x;
  const float* src = qs + ((size_t)b*L_ + l0)*D_ + d0;
  halfT* d16 = qs16 + ((size_t)b*L_ + l0)*D_ + d0;
  #pragma unroll
  for (int i = 0; i < 8; ++i) {
    int idx = i*256 + tid;
    int r = idx >> 5, c = (idx & 31)*2;
    float2 v = *(const float2*)&src[(size_t)r*D_ + c];
    half2_t p; p[0] = (halfT)v.x; p[1] = (halfT)v.y;
    *(half2_t*)&tile[r][c] = p;
    *(half2_t*)&d16[(size_t)r*D_ + c] = p;
  }
  __syncthreads();
  halfT* dT = qsT + ((size_t)b*D_ + d0)*L_ + l0;
  #pragma unroll
  for (int i = 0; i < 8; ++i) {
    int idx = i*256 + tid;
    int r = idx >> 5, c = (idx & 31)*2;
    half2_t p; p[0] = tile[c][r]; p[1] = tile[c+1][r];
    *(half2_t*)&dT[(size_t)r*L_ + c] = p;
  }
}

// ---------------- gemm_bt: C[M][N] = A[M][K] @ B[N][K]^T  (fp16 in, fp32 out) ----------------
// BM=64, BN=128, BK=64. 256 threads = 4 waves (2x2 of 32x64 wave-tiles).
// ldA = ldB = K. Grid = 8b * NT * 8mt, mt innermost, XCD-swizzled.
// MODE 0: plain store. MODE 1: scale row by invl[b*512+row].
template<int MODE>
__launch_bounds__(256, 4)
__global__ void gemm_bt(const halfT* __restrict__ Aall, const halfT* __restrict__ Ball,
                        float* __restrict__ Call, const float* __restrict__ invl,
                        int K, int NT, int ldC,
                        size_t sAb, size_t sBb, size_t sCb)
{
  __shared__ __attribute__((aligned(16))) halfT At[64*64];    //  8 KB
  __shared__ __attribute__((aligned(16))) halfT Bt[128*64];   // 16 KB

  int nwg = gridDim.x;
  int bid = blockIdx.x;
  int cpx = nwg >> 3;                       // nwg % 8 == 0 always here
  int swz = (bid & 7)*cpx + (bid >> 3);     // contiguous chunk per XCD
  int b   = swz / (NT*8);
  int rem = swz % (NT*8);
  int nt  = rem >> 3;
  int mt  = rem & 7;

  int tid = threadIdx.x;
  int w = tid >> 6, lane = tid & 63, lg = lane >> 4, li = lane & 15;
  int wr = w >> 1, wc = w & 1;
  int lrow8 = lane >> 3;          // 0..7
  int lk    = (lane & 7)*8;       // half offset within 64-half row (16B chunks)

  const halfT* Ab = Aall + b*sAb + (size_t)mt*64*K;
  const halfT* Bb = Ball + b*sBb + (size_t)nt*128*K;

  f32x4 acc[2][4];
  #pragma unroll
  for (int i=0;i<2;++i)
    #pragma unroll
    for (int j=0;j<4;++j) acc[i][j] = (f32x4){0.f,0.f,0.f,0.f};

  int nk = K >> 6;
  for (int kt = 0; kt < nk; ++kt) {
    __syncthreads();                       // previous iter's ds_reads done
    const halfT* a0 = Ab + kt*64 + lk;
    #pragma unroll
    for (int j = 0; j < 2; ++j) {          // A: rows w*16+j*8 .. +8 (1 KB per wave-issue)
      int row = w*16 + j*8;
      gload_lds16(a0 + (size_t)(row + lrow8)*K, &At[row*64]);
    }
    const halfT* b0 = Bb + kt*64 + lk;
    #pragma unroll
    for (int j = 0; j < 4; ++j) {          // B: rows w*32+j*8 .. +8
      int row = w*32 + j*8;
      gload_lds16(b0 + (size_t)(row + lrow8)*K, &Bt[row*64]);
    }
    asm volatile("s_waitcnt vmcnt(0)" ::: "memory");
    __syncthreads();                       // tile ready

    #pragma unroll
    for (int ks = 0; ks < 2; ++ks) {
      half8 Af[2], Bf[4];
      #pragma unroll
      for (int mf = 0; mf < 2; ++mf)
        Af[mf] = *(const half8*)&At[(wr*32 + mf*16 + li)*64 + ks*32 + lg*8];
      #pragma unroll
      for (int nf = 0; nf < 4; ++nf)
        Bf[nf] = *(const half8*)&Bt[(wc*64 + nf*16 + li)*64 + ks*32 + lg*8];
      #pragma unroll
      for (int mf = 0; mf < 2; ++mf)
        #pragma unroll
        for (int nf = 0; nf < 4; ++nf)
          acc[mf][nf] = __builtin_amdgcn_mfma_f32_16x16x32_f16(Af[mf], Bf[nf], acc[mf][nf], 0,0,0);
    }
  }

  // epilogue: C row = mt*64 + wr*32 + mf*16 + lg*4 + r ; col = nt*128 + wc*64 + nf*16 + li
  float* Cb = Call + b*sCb;
  int colbase = nt*128 + wc*64;
  #pragma unroll
  for (int mf = 0; mf < 2; ++mf) {
    #pragma unroll
    for (int r = 0; r < 4; ++r) {
      int row = mt*64 + wr*32 + mf*16 + lg*4 + r;
      float sc = 1.0f;
      if constexpr (MODE == 1) sc = invl[b*M_ + row];
      #pragma unroll
      for (int nf = 0; nf < 4; ++nf)
        Cb[(size_t)row*ldC + colbase + nf*16 + li] = acc[mf][nf][r] * sc;
    }
  }
}

// ---------------- row softmax: P16 = exp(S - max), invl = 1/sum ----------------
__global__ __launch_bounds__(256)
void softmax_rows(const float* __restrict__ S, halfT* __restrict__ P,
                  float* __restrict__ invl)
{
  __shared__ float red[4];
  int row = blockIdx.x;                    // 0..4095 = b*512+m
  int tid = threadIdx.x;
  const float* src = S + (size_t)row*L_;
  f32x4 v[4];
  float mx = -3.0e38f;
  #pragma unroll
  for (int i = 0; i < 4; ++i) {
    v[i] = *(const f32x4*)&src[(size_t)(i*256 + tid)*4];
    #pragma unroll
    for (int e = 0; e < 4; ++e) mx = fmaxf(mx, v[i][e]);
  }
  #pragma unroll
  for (int off = 1; off < 64; off <<= 1) mx = fmaxf(mx, __shfl_xor(mx, off));
  int w = tid >> 6;
  if ((tid & 63) == 0) red[w] = mx;
  __syncthreads();
  mx = fmaxf(fmaxf(red[0], red[1]), fmaxf(red[2], red[3]));

  float sum = 0.f;
  halfT* dst = P + (size_t)row*L_;
  #pragma unroll
  for (int i = 0; i < 4; ++i) {
    half4_t h;
    #pragma unroll
    for (int e = 0; e < 4; ++e) {
      float ev = __expf(v[i][e] - mx);
      sum += ev;
      h[e] = (halfT)ev;
    }
    *(half4_t*)&dst[(size_t)(i*256 + tid)*4] = h;
  }
  #pragma unroll
  for (int off = 1; off < 64; off <<= 1) sum += __shfl_xor(sum, off);
  __syncthreads();                          // protect red before reuse
  if ((tid & 63) == 0) red[w] = sum;
  __syncthreads();
  if (tid == 0) invl[row] = 1.0f / (red[0] + red[1] + red[2] + red[3]);
}

// ---------------- fallback (tiny ws): correct, slow fp32 ----------------
__global__ void fallback_kernel(const float* __restrict__ qs,
                                const float* __restrict__ mem,
                                float* __restrict__ out)
{
  __shared__ float w_lds[4][4096];
  __shared__ float mem_s[4][1024];
  __shared__ float redb[256];
  int blk = blockIdx.x;
  int b = blk >> 7;
  int m0 = (blk & 127)*4;
  int tid = threadIdx.x;

  for (int i = tid; i < 4*1024; i += 256)
    mem_s[i>>10][i&1023] = mem[(size_t)(m0 + (i>>10))*D_ + (i&1023)];
  __syncthreads();

  float mx[4] = {-3e38f,-3e38f,-3e38f,-3e38f};
  for (int l = tid; l < L_; l += 256) {
    const float* qp = qs + ((size_t)b*L_ + l)*D_;
    float dot[4] = {0,0,0,0};
    for (int dd = 0; dd < D_; dd += 4) {
      f32x4 qv = *(const f32x4*)(qp + dd);
      #pragma unroll
      for (int mi=0; mi<4; ++mi)
        dot[mi] += qv[0]*mem_s[mi][dd] + qv[1]*mem_s[mi][dd+1]
                 + qv[2]*mem_s[mi][dd+2] + qv[3]*mem_s[mi][dd+3];
    }
    #pragma unroll
    for (int mi=0; mi<4; ++mi) { w_lds[mi][l] = dot[mi]; mx[mi] = fmaxf(mx[mi], dot[mi]); }
  }
  float Mv[4], Zv[4];
  for (int mi=0; mi<4; ++mi) {
    redb[tid] = mx[mi]; __syncthreads();
    for (int s=128; s>0; s>>=1) { if (tid<s) redb[tid]=fmaxf(redb[tid],redb[tid+s]); __syncthreads(); }
    Mv[mi] = redb[0]; __syncthreads();
  }
  float sm[4] = {0,0,0,0};
  for (int l = tid; l < L_; l += 256)
    #pragma unroll
    for (int mi=0; mi<4; ++mi) {
      float wv = __expf(w_lds[mi][l] - Mv[mi]);
      w_lds[mi][l] = wv; sm[mi] += wv;
    }
  for (int mi=0; mi<4; ++mi) {
    redb[tid] = sm[mi]; __syncthreads();
    for (int s=128; s>0; s>>=1) { if (tid<s) redb[tid]+=redb[tid+s]; __syncthreads(); }
    Zv[mi] = redb[0]; __syncthreads();
  }
  int d0 = tid*4;
  f32x4 a[4];
  #pragma unroll
  for (int mi=0;mi<4;++mi) a[mi] = (f32x4){0,0,0,0};
  for (int l = 0; l < L_; ++l) {
    f32x4 qv = *(const f32x4*)(qs + ((size_t)b*L_ + l)*D_ + d0);
    #pragma unroll
    for (int mi=0; mi<4; ++mi) a[mi] += qv * w_lds[mi][l];
  }
  #pragma unroll
  for (int mi=0; mi<4; ++mi) {
    float invz = 1.f/Zv[mi];
    #pragma unroll
    for (int c=0; c<4; ++c)
      out[((size_t)b*M_ + m0 + mi)*D_ + d0 + c] = a[mi][c]*invz;
  }
}

extern "C" void kernel_launch(void* const* d_in, const int* in_sizes, int n_in,
                              void* d_out, int out_size, void* d_ws, size_t ws_size,
                              hipStream_t stream) {
  const float* qs  = (const float*)d_in[0];
  const float* mem = (const float*)d_in[1];
  float* out = (float*)d_out;

  // tuple output: r [8*512*1024] then memory [512*1024]
  hipMemcpyAsync(out + (size_t)B_*M_*D_, mem, (size_t)M_*D_*sizeof(float),
                 hipMemcpyDeviceToDevice, stream);

  if (ws_size >= (size_t)WS_NEED) {
    char* base = (char*)d_ws;
    halfT* qsT   = (halfT*)(base + OFF_QST);
    halfT* qs16  = (halfT*)(base + OFF_QS16);
    halfT* mem16 = (halfT*)(base + OFF_MEM16);
    float* S     = (float*)(base + OFF_S);
    float* invl  = (float*)(base + OFF_INVL);
    halfT* P16   = (halfT*)(base + OFF_P16);   // overlays qs16

    prep_mem16<<<2048, 256, 0, stream>>>(mem, mem16);
    prep_qs<<<dim3(64,16,8), 256, 0, stream>>>(qs, qs16, qsT);
    // S = mem16 @ qs16^T : M=512, N=4096, K=1024
    gemm_bt<0><<<2048, 256, 0, stream>>>(mem16, qs16, S, nullptr,
                                         1024, 32, 4096,
                                         (size_t)0, (size_t)L_*D_, (size_t)M_*L_);
    softmax_rows<<<4096, 256, 0, stream>>>(S, P16, invl);
    // r = (P16 @ qsT^T) * invl : M=512, N=1024, K=4096
    gemm_bt<1><<<512, 256, 0, stream>>>(P16, qsT, out, invl,
                                        4096, 8, 1024,
                                        (size_t)M_*L_, (size_t)D_*L_, (size_t)M_*D_);
  } else {
    fallback_kernel<<<1024, 256, 0, stream>>>(qs, mem, out);
  }
}

// Round 4
// 217.364 us; speedup vs baseline: 2.0608x; 1.0172x over previous
//
#include <hip/hip_runtime.h>
#include <hip/hip_fp16.h>

// Memory_Attention: r = softmax_L(memory @ qs^T) @ qs ; out = (r, memory)
// B=8 L=4096 D=1024 M=512, fp32 in/out.
//
// Round 4: split-K on the PV GEMM (was 94us @ 17% occupancy, 2 blocks/CU).
//   prep_mem16 / prep_qs : fp32 -> fp16 (qs16 [b][l][d], qsT [b][d][l], mem16)
//   gemm_bt              : S = mem16 @ qs16^T   (nks=1, grid 2048)
//   softmax_rows         : P16 = exp(S - rowmax) fp16, invl = 1/rowsum
//   gemm_bt              : rp[ks] = P16 @ qsT^T over K-chunk ks (nks=4, grid 2048)
//   combine_scale        : out = invl * sum_ks rp[ks]
// gemm_bt: 64x128 tile, BK=64, 4 waves, global_load_lds dwordx4, 2-barrier loop,
// linear LDS (m97 structure), XCD-swizzled. rp overlays dead S; P16 overlays qs16.

#define B_ 8
#define L_ 4096
#define D_ 1024
#define M_ 512

typedef _Float16 halfT;
typedef _Float16 half8 __attribute__((ext_vector_type(8)));
typedef _Float16 half4_t __attribute__((ext_vector_type(4)));
typedef float f32x4 __attribute__((ext_vector_type(4)));

// ---- ws layout (bytes) ----
#define OFF_QST   0ull
#define SZ_QST    (8ull*1024*4096*2)          // 67,108,864
#define OFF_QS16  (OFF_QST + SZ_QST)
#define SZ_QS16   (8ull*4096*1024*2)          // 67,108,864
#define OFF_MEM16 (OFF_QS16 + SZ_QS16)
#define SZ_MEM16  (512ull*1024*2)             //  1,048,576
#define OFF_S     (OFF_MEM16 + SZ_MEM16)
#define SZ_S      (8ull*512*4096*4)           // 67,108,864
#define OFF_INVL  (OFF_S + SZ_S)
#define SZ_INVL   (8ull*512*4)
#define WS_NEED   (OFF_INVL + SZ_INVL)        // 202,391,552 (ws known >= 202,506,240)
#define OFF_P16   OFF_QS16                    // overlay: qs16 dead after gemm1
#define OFF_RP    OFF_S                       // overlay: S dead after softmax (4*16MB = SZ_S exactly)

__device__ __forceinline__ void gload_lds16(const halfT* g, halfT* l) {
  __builtin_amdgcn_global_load_lds(
      (const __attribute__((address_space(1))) unsigned int*)(const void*)g,
      (__attribute__((address_space(3))) unsigned int*)l, 16, 0, 0);
}

// ---------------- prep kernels ----------------
__global__ void prep_mem16(const float* __restrict__ mem, halfT* __restrict__ mem16) {
  int i = blockIdx.x*256 + threadIdx.x;   // 2048*256 = 524288 exact
  mem16[i] = (halfT)mem[i];
}

// One pass over qs: write qs16 [b][l][d] and qsT [b][d][l], both fp16.
__global__ void prep_qs(const float* __restrict__ qs,
                        halfT* __restrict__ qs16, halfT* __restrict__ qsT) {
  __shared__ halfT tile[64][68];          // row stride 136B: 8B-aligned half4 stores
  int b = blockIdx.z, l0 = blockIdx.x*64, d0 = blockIdx.y*64;
  int tid = threadIdx.x;
  const float* src = qs + ((size_t)b*L_ + l0)*D_ + d0;
  halfT* d16 = qs16 + ((size_t)b*L_ + l0)*D_ + d0;
  #pragma unroll
  for (int i = 0; i < 4; ++i) {
    int idx = i*256 + tid;                // 0..1023
    int r = idx >> 4, c = (idx & 15)*4;   // r = l row, c = d col (x4)
    f32x4 v = *(const f32x4*)&src[(size_t)r*D_ + c];
    half4_t p; p[0]=(halfT)v[0]; p[1]=(halfT)v[1]; p[2]=(halfT)v[2]; p[3]=(halfT)v[3];
    *(half4_t*)&tile[r][c] = p;
    *(half4_t*)&d16[(size_t)r*D_ + c] = p;
  }
  __syncthreads();
  halfT* dT = qsT + ((size_t)b*D_ + d0)*L_ + l0;
  #pragma unroll
  for (int i = 0; i < 4; ++i) {
    int idx = i*256 + tid;
    int r = idx >> 4, c = (idx & 15)*4;   // r = d row, c = l col (x4)
    half4_t p; p[0]=tile[c][r]; p[1]=tile[c+1][r]; p[2]=tile[c+2][r]; p[3]=tile[c+3][r];
    *(half4_t*)&dT[(size_t)r*L_ + c] = p;
  }
}

// ---------------- gemm_bt: C[ks][b][M][N] = A[M][Kchunk] @ B[N][Kchunk]^T ----------------
// BM=64, BN=128, BK=64. 256 threads = 4 waves (2x2 of 32x64 wave-tiles).
// Rows of A,B have leading dim K_ld; each block covers K-chunk ks of length K_len.
// Grid = nks * B_ * NT * 8mt (mt innermost), XCD-swizzled.
__launch_bounds__(256, 4)
__global__ void gemm_bt(const halfT* __restrict__ Aall, const halfT* __restrict__ Ball,
                        float* __restrict__ Call,
                        int K_ld, int K_len, int nks, int NT, int ldC,
                        size_t sAb, size_t sBb, size_t sCb, size_t sKs)
{
  __shared__ __attribute__((aligned(16))) halfT At[64*64];    //  8 KB
  __shared__ __attribute__((aligned(16))) halfT Bt[128*64];   // 16 KB

  int nwg = gridDim.x;
  int bid = blockIdx.x;
  int cpx = nwg >> 3;                       // nwg % 8 == 0 always here
  int swz = (bid & 7)*cpx + (bid >> 3);     // contiguous chunk per XCD
  int bpk  = nwg / nks;                     // blocks per K-slice
  int ks   = swz / bpk;
  int rem  = swz % bpk;
  int b    = rem / (NT*8);
  int rem2 = rem % (NT*8);
  int nt   = rem2 >> 3;
  int mt   = rem2 & 7;

  int tid = threadIdx.x;
  int w = tid >> 6, lane = tid & 63, lg = lane >> 4, li = lane & 15;
  int wr = w >> 1, wc = w & 1;
  int lrow8 = lane >> 3;          // 0..7
  int lk    = (lane & 7)*8;       // half offset within 64-half row (16B chunks)

  const halfT* Ab = Aall + b*sAb + (size_t)mt*64*K_ld + (size_t)ks*K_len;
  const halfT* Bb = Ball + b*sBb + (size_t)nt*128*K_ld + (size_t)ks*K_len;

  f32x4 acc[2][4];
  #pragma unroll
  for (int i=0;i<2;++i)
    #pragma unroll
    for (int j=0;j<4;++j) acc[i][j] = (f32x4){0.f,0.f,0.f,0.f};

  int nk = K_len >> 6;
  for (int kt = 0; kt < nk; ++kt) {
    __syncthreads();                       // previous iter's ds_reads done
    const halfT* a0 = Ab + kt*64 + lk;
    #pragma unroll
    for (int j = 0; j < 2; ++j) {          // A rows w*16+j*8 .. +8
      int row = w*16 + j*8;
      gload_lds16(a0 + (size_t)(row + lrow8)*K_ld, &At[row*64]);
    }
    const halfT* b0 = Bb + kt*64 + lk;
    #pragma unroll
    for (int j = 0; j < 4; ++j) {          // B rows w*32+j*8 .. +8
      int row = w*32 + j*8;
      gload_lds16(b0 + (size_t)(row + lrow8)*K_ld, &Bt[row*64]);
    }
    asm volatile("s_waitcnt vmcnt(0)" ::: "memory");
    __syncthreads();                       // tile ready

    #pragma unroll
    for (int ksub = 0; ksub < 2; ++ksub) {
      half8 Af[2], Bf[4];
      #pragma unroll
      for (int mf = 0; mf < 2; ++mf)
        Af[mf] = *(const half8*)&At[(wr*32 + mf*16 + li)*64 + ksub*32 + lg*8];
      #pragma unroll
      for (int nf = 0; nf < 4; ++nf)
        Bf[nf] = *(const half8*)&Bt[(wc*64 + nf*16 + li)*64 + ksub*32 + lg*8];
      #pragma unroll
      for (int mf = 0; mf < 2; ++mf)
        #pragma unroll
        for (int nf = 0; nf < 4; ++nf)
          acc[mf][nf] = __builtin_amdgcn_mfma_f32_16x16x32_f16(Af[mf], Bf[nf], acc[mf][nf], 0,0,0);
    }
  }

  // epilogue: row = mt*64 + wr*32 + mf*16 + lg*4 + r ; col = nt*128 + wc*64 + nf*16 + li
  float* Cb = Call + (size_t)ks*sKs + b*sCb;
  int colbase = nt*128 + wc*64;
  #pragma unroll
  for (int mf = 0; mf < 2; ++mf) {
    #pragma unroll
    for (int r = 0; r < 4; ++r) {
      int row = mt*64 + wr*32 + mf*16 + lg*4 + r;
      #pragma unroll
      for (int nf = 0; nf < 4; ++nf)
        Cb[(size_t)row*ldC + colbase + nf*16 + li] = acc[mf][nf][r];
    }
  }
}

// ---------------- row softmax: P16 = exp(S - max), invl = 1/sum ----------------
__global__ __launch_bounds__(256)
void softmax_rows(const float* __restrict__ S, halfT* __restrict__ P,
                  float* __restrict__ invl)
{
  __shared__ float red[4];
  int row = blockIdx.x;                    // 0..4095 = b*512+m
  int tid = threadIdx.x;
  const float* src = S + (size_t)row*L_;
  f32x4 v[4];
  float mx = -3.0e38f;
  #pragma unroll
  for (int i = 0; i < 4; ++i) {
    v[i] = *(const f32x4*)&src[(size_t)(i*256 + tid)*4];
    #pragma unroll
    for (int e = 0; e < 4; ++e) mx = fmaxf(mx, v[i][e]);
  }
  #pragma unroll
  for (int off = 1; off < 64; off <<= 1) mx = fmaxf(mx, __shfl_xor(mx, off));
  int w = tid >> 6;
  if ((tid & 63) == 0) red[w] = mx;
  __syncthreads();
  mx = fmaxf(fmaxf(red[0], red[1]), fmaxf(red[2], red[3]));

  float sum = 0.f;
  halfT* dst = P + (size_t)row*L_;
  #pragma unroll
  for (int i = 0; i < 4; ++i) {
    half4_t h;
    #pragma unroll
    for (int e = 0; e < 4; ++e) {
      float ev = __expf(v[i][e] - mx);
      sum += ev;
      h[e] = (halfT)ev;
    }
    *(half4_t*)&dst[(size_t)(i*256 + tid)*4] = h;
  }
  #pragma unroll
  for (int off = 1; off < 64; off <<= 1) sum += __shfl_xor(sum, off);
  __syncthreads();                          // protect red before reuse
  if ((tid & 63) == 0) red[w] = sum;
  __syncthreads();
  if (tid == 0) invl[row] = 1.0f / (red[0] + red[1] + red[2] + red[3]);
}

// ---------------- combine: out = invl * sum_ks rp[ks] ----------------
__global__ __launch_bounds__(256)
void combine_scale(const float* __restrict__ rp, const float* __restrict__ invl,
                   float* __restrict__ out)
{
  int bm = blockIdx.x;                     // 0..4095
  int tid = threadIdx.x;
  size_t off = (size_t)bm*D_ + tid*4;
  f32x4 v = *(const f32x4*)&rp[off];
  #pragma unroll
  for (int s = 1; s < 4; ++s)
    v += *(const f32x4*)&rp[(size_t)s*B_*M_*D_ + off];
  float sc = invl[bm];
  v *= sc;
  *(f32x4*)&out[off] = v;
}

// ---------------- fallback (tiny ws): correct, slow fp32 ----------------
__global__ void fallback_kernel(const float* __restrict__ qs,
                                const float* __restrict__ mem,
                                float* __restrict__ out)
{
  __shared__ float w_lds[4][4096];
  __shared__ float mem_s[4][1024];
  __shared__ float redb[256];
  int blk = blockIdx.x;
  int b = blk >> 7;
  int m0 = (blk & 127)*4;
  int tid = threadIdx.x;

  for (int i = tid; i < 4*1024; i += 256)
    mem_s[i>>10][i&1023] = mem[(size_t)(m0 + (i>>10))*D_ + (i&1023)];
  __syncthreads();

  float mx[4] = {-3e38f,-3e38f,-3e38f,-3e38f};
  for (int l = tid; l < L_; l += 256) {
    const float* qp = qs + ((size_t)b*L_ + l)*D_;
    float dot[4] = {0,0,0,0};
    for (int dd = 0; dd < D_; dd += 4) {
      f32x4 qv = *(const f32x4*)(qp + dd);
      #pragma unroll
      for (int mi=0; mi<4; ++mi)
        dot[mi] += qv[0]*mem_s[mi][dd] + qv[1]*mem_s[mi][dd+1]
                 + qv[2]*mem_s[mi][dd+2] + qv[3]*mem_s[mi][dd+3];
    }
    #pragma unroll
    for (int mi=0; mi<4; ++mi) { w_lds[mi][l] = dot[mi]; mx[mi] = fmaxf(mx[mi], dot[mi]); }
  }
  float Mv[4], Zv[4];
  for (int mi=0; mi<4; ++mi) {
    redb[tid] = mx[mi]; __syncthreads();
    for (int s=128; s>0; s>>=1) { if (tid<s) redb[tid]=fmaxf(redb[tid],redb[tid+s]); __syncthreads(); }
    Mv[mi] = redb[0]; __syncthreads();
  }
  float sm[4] = {0,0,0,0};
  for (int l = tid; l < L_; l += 256)
    #pragma unroll
    for (int mi=0; mi<4; ++mi) {
      float wv = __expf(w_lds[mi][l] - Mv[mi]);
      w_lds[mi][l] = wv; sm[mi] += wv;
    }
  for (int mi=0; mi<4; ++mi) {
    redb[tid] = sm[mi]; __syncthreads();
    for (int s=128; s>0; s>>=1) { if (tid<s) redb[tid]+=redb[tid+s]; __syncthreads(); }
    Zv[mi] = redb[0]; __syncthreads();
  }
  int d0 = tid*4;
  f32x4 a[4];
  #pragma unroll
  for (int mi=0;mi<4;++mi) a[mi] = (f32x4){0,0,0,0};
  for (int l = 0; l < L_; ++l) {
    f32x4 qv = *(const f32x4*)(qs + ((size_t)b*L_ + l)*D_ + d0);
    #pragma unroll
    for (int mi=0; mi<4; ++mi) a[mi] += qv * w_lds[mi][l];
  }
  #pragma unroll
  for (int mi=0; mi<4; ++mi) {
    float invz = 1.f/Zv[mi];
    #pragma unroll
    for (int c=0; c<4; ++c)
      out[((size_t)b*M_ + m0 + mi)*D_ + d0 + c] = a[mi][c]*invz;
  }
}

extern "C" void kernel_launch(void* const* d_in, const int* in_sizes, int n_in,
                              void* d_out, int out_size, void* d_ws, size_t ws_size,
                              hipStream_t stream) {
  const float* qs  = (const float*)d_in[0];
  const float* mem = (const float*)d_in[1];
  float* out = (float*)d_out;

  // tuple output: r [8*512*1024] then memory [512*1024]
  hipMemcpyAsync(out + (size_t)B_*M_*D_, mem, (size_t)M_*D_*sizeof(float),
                 hipMemcpyDeviceToDevice, stream);

  if (ws_size >= (size_t)WS_NEED) {
    char* base = (char*)d_ws;
    halfT* qsT   = (halfT*)(base + OFF_QST);
    halfT* qs16  = (halfT*)(base + OFF_QS16);
    halfT* mem16 = (halfT*)(base + OFF_MEM16);
    float* S     = (float*)(base + OFF_S);
    float* invl  = (float*)(base + OFF_INVL);
    halfT* P16   = (halfT*)(base + OFF_P16);   // overlays qs16
    float* rp    = (float*)(base + OFF_RP);    // overlays S

    prep_mem16<<<2048, 256, 0, stream>>>(mem, mem16);
    prep_qs<<<dim3(64,16,8), 256, 0, stream>>>(qs, qs16, qsT);
    // S = mem16 @ qs16^T : per b M=512, N=4096, K=1024
    gemm_bt<<<2048, 256, 0, stream>>>(mem16, qs16, S,
                                      1024, 1024, 1, 32, 4096,
                                      (size_t)0, (size_t)L_*D_, (size_t)M_*L_, (size_t)0);
    softmax_rows<<<4096, 256, 0, stream>>>(S, P16, invl);
    // rp[ks] = P16 @ qsT^T over K-chunk : per b M=512, N=1024, Kchunk=1024, nks=4
    gemm_bt<<<2048, 256, 0, stream>>>(P16, qsT, rp,
                                      4096, 1024, 4, 8, 1024,
                                      (size_t)M_*L_, (size_t)D_*L_, (size_t)M_*D_,
                                      (size_t)B_*M_*D_);
    combine_scale<<<4096, 256, 0, stream>>>(rp, invl, out);
  } else {
    fallback_kernel<<<1024, 256, 0, stream>>>(qs, mem, out);
  }
}

// Round 5
// 216.863 us; speedup vs baseline: 2.0656x; 1.0023x over previous
//
#include <hip/hip_runtime.h>
#include <hip/hip_fp16.h>

// Memory_Attention: r = softmax_L(memory @ qs^T) @ qs ; out = (r, memory)
// B=8 L=4096 D=1024 M=512, fp32 in/out.
//
// Round 5:
//  - gemm_bt upgraded to m97 128x128 structure (BM=BN=128, BK=64, 4 waves,
//    4x4 16x16x32 frags/wave, global_load_lds dwordx4, 2-barrier loop).
//  - prep_qs rebuilt: XOR-swizzled LDS transpose (2-way write conflicts = free,
//    b128 reads at phase minimum), 16B stores for qs16 and qsT.
// Pipeline: prep_mem16, prep_qs -> gemm1 (S) -> softmax -> gemm2 split-K x4 (rp)
//           -> combine_scale. P16 overlays qs16; rp overlays S.

#define B_ 8
#define L_ 4096
#define D_ 1024
#define M_ 512

typedef _Float16 halfT;
typedef _Float16 half8 __attribute__((ext_vector_type(8)));
typedef _Float16 half4_t __attribute__((ext_vector_type(4)));
typedef float f32x4 __attribute__((ext_vector_type(4)));

// ---- ws layout (bytes) ----
#define OFF_QST   0ull
#define SZ_QST    (8ull*1024*4096*2)          // 67,108,864
#define OFF_QS16  (OFF_QST + SZ_QST)
#define SZ_QS16   (8ull*4096*1024*2)          // 67,108,864
#define OFF_MEM16 (OFF_QS16 + SZ_QS16)
#define SZ_MEM16  (512ull*1024*2)             //  1,048,576
#define OFF_S     (OFF_MEM16 + SZ_MEM16)
#define SZ_S      (8ull*512*4096*4)           // 67,108,864
#define OFF_INVL  (OFF_S + SZ_S)
#define SZ_INVL   (8ull*512*4)
#define WS_NEED   (OFF_INVL + SZ_INVL)        // 202,391,552 (ws known >= 202,506,240)
#define OFF_P16   OFF_QS16                    // overlay: qs16 dead after gemm1
#define OFF_RP    OFF_S                       // overlay: S dead after softmax

__device__ __forceinline__ void gload_lds16(const halfT* g, halfT* l) {
  __builtin_amdgcn_global_load_lds(
      (const __attribute__((address_space(1))) unsigned int*)(const void*)g,
      (__attribute__((address_space(3))) unsigned int*)l, 16, 0, 0);
}

// ---------------- prep kernels ----------------
__global__ void prep_mem16(const float* __restrict__ mem, halfT* __restrict__ mem16) {
  int i = blockIdx.x*256 + threadIdx.x;   // 2048*256 = 524288 exact
  mem16[i] = (halfT)mem[i];
}

// 64l x 64d tile. One pass over qs: qs16 [b][l][d] (direct) and qsT [b][d][l]
// (via XOR-swizzled transposed LDS tile).
// LDS layout: element (l, dd) stored at row dd, 16B-chunk position
//   q = (l>>3) ^ s(dd), s(dd) = (dd&7) ^ ((dd>>3)&7), within-chunk (l&7).
// Write banks: 2-way (free). Read: ds_read_b128 at the 8-cycle phase minimum.
__global__ __launch_bounds__(256)
void prep_qs(const float* __restrict__ qs,
             halfT* __restrict__ qs16, halfT* __restrict__ qsT) {
  __shared__ halfT tl[64*64];             // 8 KB
  int b = blockIdx.z, l0 = blockIdx.x*64, d0 = blockIdx.y*64;
  int tid = threadIdx.x;
  #pragma unroll
  for (int i = 0; i < 2; ++i) {
    int idx = i*256 + tid;                // 0..511
    int l = idx >> 3, c = idx & 7;        // l row, d-chunk (8 wide)
    const float* src = qs + ((size_t)(b*L_ + l0 + l))*D_ + d0 + c*8;
    f32x4 x0 = *(const f32x4*)src;
    f32x4 x1 = *(const f32x4*)(src + 4);
    half8 h;
    #pragma unroll
    for (int j = 0; j < 4; ++j) { h[j] = (halfT)x0[j]; h[4+j] = (halfT)x1[j]; }
    *(half8*)&qs16[((size_t)(b*L_ + l0 + l))*D_ + d0 + c*8] = h;
    int lc = l >> 3, lo = l & 7;
    #pragma unroll
    for (int j = 0; j < 8; ++j) {
      int dd = c*8 + j;                   // dd&7 = j, dd>>3 = c
      tl[dd*64 + ((lc ^ j ^ c) << 3) + lo] = h[j];
    }
  }
  __syncthreads();
  #pragma unroll
  for (int i = 0; i < 2; ++i) {
    int idx = i*256 + tid;
    int dd = idx >> 3, lc = idx & 7;
    int s = (dd & 7) ^ ((dd >> 3) & 7);
    half8 v = *(const half8*)&tl[dd*64 + ((lc ^ s) << 3)];
    *(half8*)&qsT[((size_t)(b*D_ + d0 + dd))*L_ + l0 + lc*8] = v;
  }
}

// ---------------- gemm_bt (m97 structure) ----------------
// C[ks][b][M][N] = A[M][Kchunk] @ B[N][Kchunk]^T, fp16 in fp32 out.
// BM=BN=128, BK=64. 256 threads = 4 waves (2x2), each wave 64x64 out (4x4 frags).
// Grid = nks * B_ * NT * MT (mt innermost), XCD-swizzled.
__global__ __launch_bounds__(256)
void gemm_bt(const halfT* __restrict__ Aall, const halfT* __restrict__ Ball,
             float* __restrict__ Call,
             int K_ld, int K_len, int nks, int NT, int MT, int ldC,
             size_t sAb, size_t sBb, size_t sCb, size_t sKs)
{
  __shared__ __attribute__((aligned(16))) halfT At[128*64];   // 16 KB
  __shared__ __attribute__((aligned(16))) halfT Bt[128*64];   // 16 KB

  int nwg = gridDim.x;
  int bid = blockIdx.x;
  int cpx = nwg >> 3;                       // nwg % 8 == 0 always here
  int swz = (bid & 7)*cpx + (bid >> 3);     // contiguous chunk per XCD
  int bpk  = nwg / nks;
  int ks   = swz / bpk;
  int rem  = swz % bpk;
  int b    = rem / (NT*MT);
  int rem2 = rem % (NT*MT);
  int nt   = rem2 / MT;
  int mt   = rem2 % MT;

  int tid = threadIdx.x;
  int w = tid >> 6, lane = tid & 63, lg = lane >> 4, li = lane & 15;
  int wr = w >> 1, wc = w & 1;
  int lrow8 = lane >> 3;          // 0..7
  int lk    = (lane & 7)*8;       // half offset within 64-half row (16B chunks)

  const halfT* Ab = Aall + b*sAb + (size_t)mt*128*K_ld + (size_t)ks*K_len;
  const halfT* Bb = Ball + b*sBb + (size_t)nt*128*K_ld + (size_t)ks*K_len;

  f32x4 acc[4][4];
  #pragma unroll
  for (int i=0;i<4;++i)
    #pragma unroll
    for (int j=0;j<4;++j) acc[i][j] = (f32x4){0.f,0.f,0.f,0.f};

  int nk = K_len >> 6;
  for (int kt = 0; kt < nk; ++kt) {
    __syncthreads();                       // previous iter's ds_reads done
    const halfT* a0 = Ab + kt*64 + lk;
    const halfT* b0 = Bb + kt*64 + lk;
    #pragma unroll
    for (int j = 0; j < 4; ++j) {          // wave w stages rows w*32+j*8 .. +8
      int row = w*32 + j*8;
      gload_lds16(a0 + (size_t)(row + lrow8)*K_ld, &At[row*64]);
      gload_lds16(b0 + (size_t)(row + lrow8)*K_ld, &Bt[row*64]);
    }
    asm volatile("s_waitcnt vmcnt(0)" ::: "memory");
    __syncthreads();                       // tile ready

    #pragma unroll
    for (int ksub = 0; ksub < 2; ++ksub) {
      half8 Af[4], Bf[4];
      #pragma unroll
      for (int mf = 0; mf < 4; ++mf)
        Af[mf] = *(const half8*)&At[(wr*64 + mf*16 + li)*64 + ksub*32 + lg*8];
      #pragma unroll
      for (int nf = 0; nf < 4; ++nf)
        Bf[nf] = *(const half8*)&Bt[(wc*64 + nf*16 + li)*64 + ksub*32 + lg*8];
      #pragma unroll
      for (int mf = 0; mf < 4; ++mf)
        #pragma unroll
        for (int nf = 0; nf < 4; ++nf)
          acc[mf][nf] = __builtin_amdgcn_mfma_f32_16x16x32_f16(Af[mf], Bf[nf], acc[mf][nf], 0,0,0);
    }
  }

  // epilogue: row = mt*128 + wr*64 + mf*16 + lg*4 + r ; col = nt*128 + wc*64 + nf*16 + li
  float* Cb = Call + (size_t)ks*sKs + b*sCb;
  int colbase = nt*128 + wc*64;
  #pragma unroll
  for (int mf = 0; mf < 4; ++mf) {
    #pragma unroll
    for (int r = 0; r < 4; ++r) {
      int row = mt*128 + wr*64 + mf*16 + lg*4 + r;
      #pragma unroll
      for (int nf = 0; nf < 4; ++nf)
        Cb[(size_t)row*ldC + colbase + nf*16 + li] = acc[mf][nf][r];
    }
  }
}

// ---------------- row softmax: P16 = exp(S - max), invl = 1/sum ----------------
__global__ __launch_bounds__(256)
void softmax_rows(const float* __restrict__ S, halfT* __restrict__ P,
                  float* __restrict__ invl)
{
  __shared__ float red[4];
  int row = blockIdx.x;                    // 0..4095 = b*512+m
  int tid = threadIdx.x;
  const float* src = S + (size_t)row*L_;
  f32x4 v[4];
  float mx = -3.0e38f;
  #pragma unroll
  for (int i = 0; i < 4; ++i) {
    v[i] = *(const f32x4*)&src[(size_t)(i*256 + tid)*4];
    #pragma unroll
    for (int e = 0; e < 4; ++e) mx = fmaxf(mx, v[i][e]);
  }
  #pragma unroll
  for (int off = 1; off < 64; off <<= 1) mx = fmaxf(mx, __shfl_xor(mx, off));
  int w = tid >> 6;
  if ((tid & 63) == 0) red[w] = mx;
  __syncthreads();
  mx = fmaxf(fmaxf(red[0], red[1]), fmaxf(red[2], red[3]));

  float sum = 0.f;
  halfT* dst = P + (size_t)row*L_;
  #pragma unroll
  for (int i = 0; i < 4; ++i) {
    half4_t h;
    #pragma unroll
    for (int e = 0; e < 4; ++e) {
      float ev = __expf(v[i][e] - mx);
      sum += ev;
      h[e] = (halfT)ev;
    }
    *(half4_t*)&dst[(size_t)(i*256 + tid)*4] = h;
  }
  #pragma unroll
  for (int off = 1; off < 64; off <<= 1) sum += __shfl_xor(sum, off);
  __syncthreads();                          // protect red before reuse
  if ((tid & 63) == 0) red[w] = sum;
  __syncthreads();
  if (tid == 0) invl[row] = 1.0f / (red[0] + red[1] + red[2] + red[3]);
}

// ---------------- combine: out = invl * sum_ks rp[ks] ----------------
__global__ __launch_bounds__(256)
void combine_scale(const float* __restrict__ rp, const float* __restrict__ invl,
                   float* __restrict__ out)
{
  int bm = blockIdx.x;                     // 0..4095
  int tid = threadIdx.x;
  size_t off = (size_t)bm*D_ + tid*4;
  f32x4 v = *(const f32x4*)&rp[off];
  #pragma unroll
  for (int s = 1; s < 4; ++s)
    v += *(const f32x4*)&rp[(size_t)s*B_*M_*D_ + off];
  float sc = invl[bm];
  v *= sc;
  *(f32x4*)&out[off] = v;
}

// ---------------- fallback (tiny ws): correct, slow fp32 ----------------
__global__ void fallback_kernel(const float* __restrict__ qs,
                                const float* __restrict__ mem,
                                float* __restrict__ out)
{
  __shared__ float w_lds[4][4096];
  __shared__ float mem_s[4][1024];
  __shared__ float redb[256];
  int blk = blockIdx.x;
  int b = blk >> 7;
  int m0 = (blk & 127)*4;
  int tid = threadIdx.x;

  for (int i = tid; i < 4*1024; i += 256)
    mem_s[i>>10][i&1023] = mem[(size_t)(m0 + (i>>10))*D_ + (i&1023)];
  __syncthreads();

  float mx[4] = {-3e38f,-3e38f,-3e38f,-3e38f};
  for (int l = tid; l < L_; l += 256) {
    const float* qp = qs + ((size_t)b*L_ + l)*D_;
    float dot[4] = {0,0,0,0};
    for (int dd = 0; dd < D_; dd += 4) {
      f32x4 qv = *(const f32x4*)(qp + dd);
      #pragma unroll
      for (int mi=0; mi<4; ++mi)
        dot[mi] += qv[0]*mem_s[mi][dd] + qv[1]*mem_s[mi][dd+1]
                 + qv[2]*mem_s[mi][dd+2] + qv[3]*mem_s[mi][dd+3];
    }
    #pragma unroll
    for (int mi=0; mi<4; ++mi) { w_lds[mi][l] = dot[mi]; mx[mi] = fmaxf(mx[mi], dot[mi]); }
  }
  float Mv[4], Zv[4];
  for (int mi=0; mi<4; ++mi) {
    redb[tid] = mx[mi]; __syncthreads();
    for (int s=128; s>0; s>>=1) { if (tid<s) redb[tid]=fmaxf(redb[tid],redb[tid+s]); __syncthreads(); }
    Mv[mi] = redb[0]; __syncthreads();
  }
  float sm[4] = {0,0,0,0};
  for (int l = tid; l < L_; l += 256)
    #pragma unroll
    for (int mi=0; mi<4; ++mi) {
      float wv = __expf(w_lds[mi][l] - Mv[mi]);
      w_lds[mi][l] = wv; sm[mi] += wv;
    }
  for (int mi=0; mi<4; ++mi) {
    redb[tid] = sm[mi]; __syncthreads();
    for (int s=128; s>0; s>>=1) { if (tid<s) redb[tid]+=redb[tid+s]; __syncthreads(); }
    Zv[mi] = redb[0]; __syncthreads();
  }
  int d0 = tid*4;
  f32x4 a[4];
  #pragma unroll
  for (int mi=0;mi<4;++mi) a[mi] = (f32x4){0,0,0,0};
  for (int l = 0; l < L_; ++l) {
    f32x4 qv = *(const f32x4*)(qs + ((size_t)b*L_ + l)*D_ + d0);
    #pragma unroll
    for (int mi=0; mi<4; ++mi) a[mi] += qv * w_lds[mi][l];
  }
  #pragma unroll
  for (int mi=0; mi<4; ++mi) {
    float invz = 1.f/Zv[mi];
    #pragma unroll
    for (int c=0; c<4; ++c)
      out[((size_t)b*M_ + m0 + mi)*D_ + d0 + c] = a[mi][c]*invz;
  }
}

extern "C" void kernel_launch(void* const* d_in, const int* in_sizes, int n_in,
                              void* d_out, int out_size, void* d_ws, size_t ws_size,
                              hipStream_t stream) {
  const float* qs  = (const float*)d_in[0];
  const float* mem = (const float*)d_in[1];
  float* out = (float*)d_out;

  // tuple output: r [8*512*1024] then memory [512*1024]
  hipMemcpyAsync(out + (size_t)B_*M_*D_, mem, (size_t)M_*D_*sizeof(float),
                 hipMemcpyDeviceToDevice, stream);

  if (ws_size >= (size_t)WS_NEED) {
    char* base = (char*)d_ws;
    halfT* qsT   = (halfT*)(base + OFF_QST);
    halfT* qs16  = (halfT*)(base + OFF_QS16);
    halfT* mem16 = (halfT*)(base + OFF_MEM16);
    float* S     = (float*)(base + OFF_S);
    float* invl  = (float*)(base + OFF_INVL);
    halfT* P16   = (halfT*)(base + OFF_P16);   // overlays qs16
    float* rp    = (float*)(base + OFF_RP);    // overlays S

    prep_mem16<<<2048, 256, 0, stream>>>(mem, mem16);
    prep_qs<<<dim3(64,16,8), 256, 0, stream>>>(qs, qs16, qsT);
    // S = mem16 @ qs16^T : per b M=512, N=4096, K=1024 ; MT=4, NT=32
    gemm_bt<<<1024, 256, 0, stream>>>(mem16, qs16, S,
                                      1024, 1024, 1, 32, 4, 4096,
                                      (size_t)0, (size_t)L_*D_, (size_t)M_*L_, (size_t)0);
    softmax_rows<<<4096, 256, 0, stream>>>(S, P16, invl);
    // rp[ks] = P16 @ qsT^T : per b M=512, N=1024, Kchunk=1024, nks=4 ; MT=4, NT=8
    gemm_bt<<<1024, 256, 0, stream>>>(P16, qsT, rp,
                                      4096, 1024, 4, 8, 4, 1024,
                                      (size_t)M_*L_, (size_t)D_*L_, (size_t)M_*D_,
                                      (size_t)B_*M_*D_);
    combine_scale<<<4096, 256, 0, stream>>>(rp, invl, out);
  } else {
    fallback_kernel<<<1024, 256, 0, stream>>>(qs, mem, out);
  }
}

// Round 6
// 190.973 us; speedup vs baseline: 2.3456x; 1.1356x over previous
//
#include <hip/hip_runtime.h>
#include <hip/hip_fp16.h>

// Memory_Attention: r = softmax_L(memory @ qs^T) @ qs ; out = (r, memory)
// B=8 L=4096 D=1024 M=512, fp32 in/out.
//
// Round 6: gemm_bt rebuilt as 256x256 tile, 8-wave, double-buffered 2-phase
// prefetch loop (T3 minimum recipe): STAGE(next) issued BEFORE compute(cur),
// single __syncthreads per K-step (implicit vmcnt(0) drain covered by MFMA).
// Pipeline: prep_mem16, prep_qs -> gemm1 (S) -> softmax -> gemm2 split-K x4 (rp)
//           -> combine_scale. P16 overlays qs16; rp overlays S.

#define B_ 8
#define L_ 4096
#define D_ 1024
#define M_ 512

typedef _Float16 halfT;
typedef _Float16 half8 __attribute__((ext_vector_type(8)));
typedef _Float16 half4_t __attribute__((ext_vector_type(4)));
typedef float f32x4 __attribute__((ext_vector_type(4)));

// ---- ws layout (bytes) ----
#define OFF_QST   0ull
#define SZ_QST    (8ull*1024*4096*2)          // 67,108,864
#define OFF_QS16  (OFF_QST + SZ_QST)
#define SZ_QS16   (8ull*4096*1024*2)          // 67,108,864
#define OFF_MEM16 (OFF_QS16 + SZ_QS16)
#define SZ_MEM16  (512ull*1024*2)             //  1,048,576
#define OFF_S     (OFF_MEM16 + SZ_MEM16)
#define SZ_S      (8ull*512*4096*4)           // 67,108,864
#define OFF_INVL  (OFF_S + SZ_S)
#define SZ_INVL   (8ull*512*4)
#define WS_NEED   (OFF_INVL + SZ_INVL)        // 202,391,552 (ws known >= 202,506,240)
#define OFF_P16   OFF_QS16                    // overlay: qs16 dead after gemm1
#define OFF_RP    OFF_S                       // overlay: S dead after softmax

__device__ __forceinline__ void gload_lds16(const halfT* g, halfT* l) {
  __builtin_amdgcn_global_load_lds(
      (const __attribute__((address_space(1))) unsigned int*)(const void*)g,
      (__attribute__((address_space(3))) unsigned int*)l, 16, 0, 0);
}

// ---------------- prep kernels ----------------
__global__ void prep_mem16(const float* __restrict__ mem, halfT* __restrict__ mem16) {
  int i = blockIdx.x*256 + threadIdx.x;   // 2048*256 = 524288 exact
  mem16[i] = (halfT)mem[i];
}

// 64l x 64d tile. One pass over qs: qs16 [b][l][d] (direct) and qsT [b][d][l]
// (via XOR-swizzled transposed LDS tile).
__global__ __launch_bounds__(256)
void prep_qs(const float* __restrict__ qs,
             halfT* __restrict__ qs16, halfT* __restrict__ qsT) {
  __shared__ halfT tl[64*64];             // 8 KB
  int b = blockIdx.z, l0 = blockIdx.x*64, d0 = blockIdx.y*64;
  int tid = threadIdx.x;
  #pragma unroll
  for (int i = 0; i < 2; ++i) {
    int idx = i*256 + tid;                // 0..511
    int l = idx >> 3, c = idx & 7;        // l row, d-chunk (8 wide)
    const float* src = qs + ((size_t)(b*L_ + l0 + l))*D_ + d0 + c*8;
    f32x4 x0 = *(const f32x4*)src;
    f32x4 x1 = *(const f32x4*)(src + 4);
    half8 h;
    #pragma unroll
    for (int j = 0; j < 4; ++j) { h[j] = (halfT)x0[j]; h[4+j] = (halfT)x1[j]; }
    *(half8*)&qs16[((size_t)(b*L_ + l0 + l))*D_ + d0 + c*8] = h;
    int lc = l >> 3, lo = l & 7;
    #pragma unroll
    for (int j = 0; j < 8; ++j) {
      int dd = c*8 + j;                   // dd&7 = j, dd>>3 = c
      tl[dd*64 + ((lc ^ j ^ c) << 3) + lo] = h[j];
    }
  }
  __syncthreads();
  #pragma unroll
  for (int i = 0; i < 2; ++i) {
    int idx = i*256 + tid;
    int dd = idx >> 3, lc = idx & 7;
    int s = (dd & 7) ^ ((dd >> 3) & 7);
    half8 v = *(const half8*)&tl[dd*64 + ((lc ^ s) << 3)];
    *(half8*)&qsT[((size_t)(b*D_ + d0 + dd))*L_ + l0 + lc*8] = v;
  }
}

// ---------------- gemm_bt (256^2, 8-wave, 2-phase dbuf prefetch) ----------------
// C[ks][b][M][N] = A[M][Kchunk] @ B[N][Kchunk]^T, fp16 in fp32 out.
// BM=BN=256, BK=64. 512 threads = 8 waves (2M x 4N), each wave 128x64 out
// (8x4 16x16x32 frags). Grid = nks * B_ * NT * MT (mt innermost), XCD-swizzled.
__global__ __launch_bounds__(512, 2)
void gemm_bt(const halfT* __restrict__ Aall, const halfT* __restrict__ Ball,
             float* __restrict__ Call,
             int K_ld, int K_len, int nks, int NT, int MT, int ldC,
             size_t sAb, size_t sBb, size_t sCb, size_t sKs)
{
  __shared__ __attribute__((aligned(16))) halfT Alds[2][256*64];   // 2 x 32 KB
  __shared__ __attribute__((aligned(16))) halfT Blds[2][256*64];   // 2 x 32 KB

  int nwg = gridDim.x;
  int bid = blockIdx.x;
  int cpx = nwg >> 3;                       // nwg % 8 == 0 always here
  int swz = (bid & 7)*cpx + (bid >> 3);     // contiguous chunk per XCD
  int bpk  = nwg / nks;
  int ks   = swz / bpk;
  int rem  = swz % bpk;
  int b    = rem / (NT*MT);
  int rem2 = rem % (NT*MT);
  int nt   = rem2 / MT;
  int mt   = rem2 % MT;

  int tid = threadIdx.x;
  int w = tid >> 6, lane = tid & 63, lg = lane >> 4, li = lane & 15;
  int wm = w >> 2, wn = w & 3;
  int rA = tid >> 3;              // staging row base (0..63), +64 per j
  int cA = (tid & 7)*8;           // staging col (halfs)

  const halfT* Ab = Aall + b*sAb + (size_t)mt*256*K_ld + (size_t)ks*K_len;
  const halfT* Bb = Ball + b*sBb + (size_t)nt*256*K_ld + (size_t)ks*K_len;

  f32x4 acc[8][4];
  #pragma unroll
  for (int i=0;i<8;++i)
    #pragma unroll
    for (int j=0;j<4;++j) acc[i][j] = (f32x4){0.f,0.f,0.f,0.f};

#define STAGE(nb_, kt_)                                                        \
  do {                                                                         \
    const halfT* a0 = Ab + (size_t)(kt_)*64 + cA;                              \
    const halfT* b0 = Bb + (size_t)(kt_)*64 + cA;                              \
    _Pragma("unroll")                                                          \
    for (int j = 0; j < 4; ++j) {                                              \
      int r = rA + j*64;                                                       \
      gload_lds16(a0 + (size_t)r*K_ld, &Alds[nb_][(tid + j*512)*8]);           \
      gload_lds16(b0 + (size_t)r*K_ld, &Blds[nb_][(tid + j*512)*8]);           \
    }                                                                          \
  } while (0)

  int nk = K_len >> 6;
  int nb = 0;
  STAGE(0, 0);
  __syncthreads();                         // prologue drain (vmcnt0 + barrier)

  for (int kt = 0; kt < nk; ++kt) {
    if (kt + 1 < nk) STAGE(nb ^ 1, kt + 1);   // prefetch next K-tile first
    #pragma unroll
    for (int ksub = 0; ksub < 2; ++ksub) {
      half8 Af[8], Bf[4];
      #pragma unroll
      for (int mf = 0; mf < 8; ++mf)
        Af[mf] = *(const half8*)&Alds[nb][(wm*128 + mf*16 + li)*64 + ksub*32 + lg*8];
      #pragma unroll
      for (int nf = 0; nf < 4; ++nf)
        Bf[nf] = *(const half8*)&Blds[nb][(wn*64 + nf*16 + li)*64 + ksub*32 + lg*8];
      #pragma unroll
      for (int mf = 0; mf < 8; ++mf)
        #pragma unroll
        for (int nf = 0; nf < 4; ++nf)
          acc[mf][nf] = __builtin_amdgcn_mfma_f32_16x16x32_f16(Af[mf], Bf[nf], acc[mf][nf], 0,0,0);
    }
    __syncthreads();                       // drains prefetch (vmcnt0) + lds reads
    nb ^= 1;
  }
#undef STAGE

  // epilogue: row = mt*256 + wm*128 + mf*16 + lg*4 + r ; col = nt*256 + wn*64 + nf*16 + li
  float* Cb = Call + (size_t)ks*sKs + b*sCb;
  int colbase = nt*256 + wn*64;
  #pragma unroll
  for (int mf = 0; mf < 8; ++mf) {
    #pragma unroll
    for (int r = 0; r < 4; ++r) {
      int row = mt*256 + wm*128 + mf*16 + lg*4 + r;
      #pragma unroll
      for (int nf = 0; nf < 4; ++nf)
        Cb[(size_t)row*ldC + colbase + nf*16 + li] = acc[mf][nf][r];
    }
  }
}

// ---------------- row softmax: P16 = exp(S - max), invl = 1/sum ----------------
__global__ __launch_bounds__(256)
void softmax_rows(const float* __restrict__ S, halfT* __restrict__ P,
                  float* __restrict__ invl)
{
  __shared__ float red[4];
  int row = blockIdx.x;                    // 0..4095 = b*512+m
  int tid = threadIdx.x;
  const float* src = S + (size_t)row*L_;
  f32x4 v[4];
  float mx = -3.0e38f;
  #pragma unroll
  for (int i = 0; i < 4; ++i) {
    v[i] = *(const f32x4*)&src[(size_t)(i*256 + tid)*4];
    #pragma unroll
    for (int e = 0; e < 4; ++e) mx = fmaxf(mx, v[i][e]);
  }
  #pragma unroll
  for (int off = 1; off < 64; off <<= 1) mx = fmaxf(mx, __shfl_xor(mx, off));
  int w = tid >> 6;
  if ((tid & 63) == 0) red[w] = mx;
  __syncthreads();
  mx = fmaxf(fmaxf(red[0], red[1]), fmaxf(red[2], red[3]));

  float sum = 0.f;
  halfT* dst = P + (size_t)row*L_;
  #pragma unroll
  for (int i = 0; i < 4; ++i) {
    half4_t h;
    #pragma unroll
    for (int e = 0; e < 4; ++e) {
      float ev = __expf(v[i][e] - mx);
      sum += ev;
      h[e] = (halfT)ev;
    }
    *(half4_t*)&dst[(size_t)(i*256 + tid)*4] = h;
  }
  #pragma unroll
  for (int off = 1; off < 64; off <<= 1) sum += __shfl_xor(sum, off);
  __syncthreads();                          // protect red before reuse
  if ((tid & 63) == 0) red[w] = sum;
  __syncthreads();
  if (tid == 0) invl[row] = 1.0f / (red[0] + red[1] + red[2] + red[3]);
}

// ---------------- combine: out = invl * sum_ks rp[ks] ----------------
__global__ __launch_bounds__(256)
void combine_scale(const float* __restrict__ rp, const float* __restrict__ invl,
                   float* __restrict__ out)
{
  int bm = blockIdx.x;                     // 0..4095
  int tid = threadIdx.x;
  size_t off = (size_t)bm*D_ + tid*4;
  f32x4 v = *(const f32x4*)&rp[off];
  #pragma unroll
  for (int s = 1; s < 4; ++s)
    v += *(const f32x4*)&rp[(size_t)s*B_*M_*D_ + off];
  float sc = invl[bm];
  v *= sc;
  *(f32x4*)&out[off] = v;
}

// ---------------- fallback (tiny ws): correct, slow fp32 ----------------
__global__ void fallback_kernel(const float* __restrict__ qs,
                                const float* __restrict__ mem,
                                float* __restrict__ out)
{
  __shared__ float w_lds[4][4096];
  __shared__ float mem_s[4][1024];
  __shared__ float redb[256];
  int blk = blockIdx.x;
  int b = blk >> 7;
  int m0 = (blk & 127)*4;
  int tid = threadIdx.x;

  for (int i = tid; i < 4*1024; i += 256)
    mem_s[i>>10][i&1023] = mem[(size_t)(m0 + (i>>10))*D_ + (i&1023)];
  __syncthreads();

  float mx[4] = {-3e38f,-3e38f,-3e38f,-3e38f};
  for (int l = tid; l < L_; l += 256) {
    const float* qp = qs + ((size_t)b*L_ + l)*D_;
    float dot[4] = {0,0,0,0};
    for (int dd = 0; dd < D_; dd += 4) {
      f32x4 qv = *(const f32x4*)(qp + dd);
      #pragma unroll
      for (int mi=0; mi<4; ++mi)
        dot[mi] += qv[0]*mem_s[mi][dd] + qv[1]*mem_s[mi][dd+1]
                 + qv[2]*mem_s[mi][dd+2] + qv[3]*mem_s[mi][dd+3];
    }
    #pragma unroll
    for (int mi=0; mi<4; ++mi) { w_lds[mi][l] = dot[mi]; mx[mi] = fmaxf(mx[mi], dot[mi]); }
  }
  float Mv[4], Zv[4];
  for (int mi=0; mi<4; ++mi) {
    redb[tid] = mx[mi]; __syncthreads();
    for (int s=128; s>0; s>>=1) { if (tid<s) redb[tid]=fmaxf(redb[tid],redb[tid+s]); __syncthreads(); }
    Mv[mi] = redb[0]; __syncthreads();
  }
  float sm[4] = {0,0,0,0};
  for (int l = tid; l < L_; l += 256)
    #pragma unroll
    for (int mi=0; mi<4; ++mi) {
      float wv = __expf(w_lds[mi][l] - Mv[mi]);
      w_lds[mi][l] = wv; sm[mi] += wv;
    }
  for (int mi=0; mi<4; ++mi) {
    redb[tid] = sm[mi]; __syncthreads();
    for (int s=128; s>0; s>>=1) { if (tid<s) redb[tid]+=redb[tid+s]; __syncthreads(); }
    Zv[mi] = redb[0]; __syncthreads();
  }
  int d0 = tid*4;
  f32x4 a[4];
  #pragma unroll
  for (int mi=0;mi<4;++mi) a[mi] = (f32x4){0,0,0,0};
  for (int l = 0; l < L_; ++l) {
    f32x4 qv = *(const f32x4*)(qs + ((size_t)b*L_ + l)*D_ + d0);
    #pragma unroll
    for (int mi=0; mi<4; ++mi) a[mi] += qv * w_lds[mi][l];
  }
  #pragma unroll
  for (int mi=0; mi<4; ++mi) {
    float invz = 1.f/Zv[mi];
    #pragma unroll
    for (int c=0; c<4; ++c)
      out[((size_t)b*M_ + m0 + mi)*D_ + d0 + c] = a[mi][c]*invz;
  }
}

extern "C" void kernel_launch(void* const* d_in, const int* in_sizes, int n_in,
                              void* d_out, int out_size, void* d_ws, size_t ws_size,
                              hipStream_t stream) {
  const float* qs  = (const float*)d_in[0];
  const float* mem = (const float*)d_in[1];
  float* out = (float*)d_out;

  // tuple output: r [8*512*1024] then memory [512*1024]
  hipMemcpyAsync(out + (size_t)B_*M_*D_, mem, (size_t)M_*D_*sizeof(float),
                 hipMemcpyDeviceToDevice, stream);

  if (ws_size >= (size_t)WS_NEED) {
    char* base = (char*)d_ws;
    halfT* qsT   = (halfT*)(base + OFF_QST);
    halfT* qs16  = (halfT*)(base + OFF_QS16);
    halfT* mem16 = (halfT*)(base + OFF_MEM16);
    float* S     = (float*)(base + OFF_S);
    float* invl  = (float*)(base + OFF_INVL);
    halfT* P16   = (halfT*)(base + OFF_P16);   // overlays qs16
    float* rp    = (float*)(base + OFF_RP);    // overlays S

    prep_mem16<<<2048, 256, 0, stream>>>(mem, mem16);
    prep_qs<<<dim3(64,16,8), 256, 0, stream>>>(qs, qs16, qsT);
    // S = mem16 @ qs16^T : per b M=512, N=4096, K=1024 ; MT=2, NT=16
    gemm_bt<<<256, 512, 0, stream>>>(mem16, qs16, S,
                                     1024, 1024, 1, 16, 2, 4096,
                                     (size_t)0, (size_t)L_*D_, (size_t)M_*L_, (size_t)0);
    softmax_rows<<<4096, 256, 0, stream>>>(S, P16, invl);
    // rp[ks] = P16 @ qsT^T : per b M=512, N=1024, Kchunk=1024, nks=4 ; MT=2, NT=4
    gemm_bt<<<256, 512, 0, stream>>>(P16, qsT, rp,
                                     4096, 1024, 4, 4, 2, 1024,
                                     (size_t)M_*L_, (size_t)D_*L_, (size_t)M_*D_,
                                     (size_t)B_*M_*D_);
    combine_scale<<<4096, 256, 0, stream>>>(rp, invl, out);
  } else {
    fallback_kernel<<<1024, 256, 0, stream>>>(qs, mem, out);
  }
}

// Round 7
// 189.903 us; speedup vs baseline: 2.3588x; 1.0056x over previous
//
#include <hip/hip_runtime.h>
#include <hip/hip_fp16.h>

// Memory_Attention: r = softmax_L(memory @ qs^T) @ qs ; out = (r, memory)
// B=8 L=4096 D=1024 M=512, fp32 in/out.
//
// Round 7: prep_qs restructured for DRAM burst locality.
//   Tile 256l x 64d, 256 thr, 32KB LDS. qsT writes = 512B contiguous bursts
//   (was 128B @ 8KB stride, measured 2.7 TB/s). XOR-chunk swizzle keeps the
//   transposed scalar LDS writes conflict-free (verified bank math; r5 scheme
//   measured SQ_LDS_BANK_CONFLICT=0).
// Pipeline: prep_mem16, prep_qs -> gemm1 (S) -> softmax -> gemm2 split-K x4 (rp)
//           -> combine_scale. P16 overlays qs16; rp overlays S.
// gemm_bt: 256^2 tile, 8 waves, 2-phase dbuf prefetch (round 6, unchanged).

#define B_ 8
#define L_ 4096
#define D_ 1024
#define M_ 512

typedef _Float16 halfT;
typedef _Float16 half8 __attribute__((ext_vector_type(8)));
typedef _Float16 half4_t __attribute__((ext_vector_type(4)));
typedef float f32x4 __attribute__((ext_vector_type(4)));

// ---- ws layout (bytes) ----
#define OFF_QST   0ull
#define SZ_QST    (8ull*1024*4096*2)          // 67,108,864
#define OFF_QS16  (OFF_QST + SZ_QST)
#define SZ_QS16   (8ull*4096*1024*2)          // 67,108,864
#define OFF_MEM16 (OFF_QS16 + SZ_QS16)
#define SZ_MEM16  (512ull*1024*2)             //  1,048,576
#define OFF_S     (OFF_MEM16 + SZ_MEM16)
#define SZ_S      (8ull*512*4096*4)           // 67,108,864
#define OFF_INVL  (OFF_S + SZ_S)
#define SZ_INVL   (8ull*512*4)
#define WS_NEED   (OFF_INVL + SZ_INVL)        // 202,391,552 (ws known >= 202,506,240)
#define OFF_P16   OFF_QS16                    // overlay: qs16 dead after gemm1
#define OFF_RP    OFF_S                       // overlay: S dead after softmax

__device__ __forceinline__ void gload_lds16(const halfT* g, halfT* l) {
  __builtin_amdgcn_global_load_lds(
      (const __attribute__((address_space(1))) unsigned int*)(const void*)g,
      (__attribute__((address_space(3))) unsigned int*)l, 16, 0, 0);
}

// ---------------- prep kernels ----------------
__global__ void prep_mem16(const float* __restrict__ mem, halfT* __restrict__ mem16) {
  int i = blockIdx.x*256 + threadIdx.x;   // 2048*256 = 524288 exact
  mem16[i] = (halfT)mem[i];
}

// 256l x 64d tile. One pass over qs: qs16 [b][l][d] (direct) and qsT [b][d][l]
// (via XOR-swizzled transposed LDS tile; qsT writes in 512B bursts).
// LDS: row dd (64 rows), 32 chunks of 8 halfs. Element (l,dd) at
//   chunk = (l>>3) ^ s(dd), s(dd) = (dd&7) ^ (dd>>3), offset l&7.
// Phase-1 scalar writes: conflict-free (c spans 8 banks x lo/2 quarters).
// Phase-2 b128 reads: 2-way (free). qsT stores: 32 lanes x 16B = 512B/row.
__global__ __launch_bounds__(256)
void prep_qs(const float* __restrict__ qs,
             halfT* __restrict__ qs16, halfT* __restrict__ qsT) {
  __shared__ halfT tl[64*256];             // 32 KB
  int b = blockIdx.z, l0 = blockIdx.x*256, d0 = blockIdx.y*64;
  int tid = threadIdx.x;
  #pragma unroll
  for (int i = 0; i < 8; ++i) {
    int idx = i*256 + tid;                 // 0..2047
    int l = idx >> 3, c = idx & 7;         // l row (0..255), d-chunk (8 wide)
    const float* src = qs + ((size_t)(b*L_ + l0 + l))*D_ + d0 + c*8;
    f32x4 x0 = *(const f32x4*)src;
    f32x4 x1 = *(const f32x4*)(src + 4);
    half8 h;
    #pragma unroll
    for (int j = 0; j < 4; ++j) { h[j] = (halfT)x0[j]; h[4+j] = (halfT)x1[j]; }
    *(half8*)&qs16[((size_t)(b*L_ + l0 + l))*D_ + d0 + c*8] = h;
    int lc = l >> 3, lo = l & 7;
    #pragma unroll
    for (int j = 0; j < 8; ++j) {
      int dd = c*8 + j;                    // dd&7 = j, dd>>3 = c
      int chunk = lc ^ (j ^ c);            // lc in 0..31, s in 0..7
      tl[dd*256 + chunk*8 + lo] = h[j];
    }
  }
  __syncthreads();
  #pragma unroll
  for (int i = 0; i < 8; ++i) {
    int idx = i*256 + tid;                 // 0..2047
    int dd = idx >> 5, k = idx & 31;       // dd row (0..63), l-chunk (0..31)
    int s = (dd & 7) ^ (dd >> 3);
    half8 v = *(const half8*)&tl[dd*256 + (k ^ s)*8];
    *(half8*)&qsT[((size_t)(b*D_ + d0 + dd))*L_ + l0 + k*8] = v;
  }
}

// ---------------- gemm_bt (256^2, 8-wave, 2-phase dbuf prefetch) ----------------
// C[ks][b][M][N] = A[M][Kchunk] @ B[N][Kchunk]^T, fp16 in fp32 out.
// BM=BN=256, BK=64. 512 threads = 8 waves (2M x 4N), each wave 128x64 out
// (8x4 16x16x32 frags). Grid = nks * B_ * NT * MT (mt innermost), XCD-swizzled.
__global__ __launch_bounds__(512, 2)
void gemm_bt(const halfT* __restrict__ Aall, const halfT* __restrict__ Ball,
             float* __restrict__ Call,
             int K_ld, int K_len, int nks, int NT, int MT, int ldC,
             size_t sAb, size_t sBb, size_t sCb, size_t sKs)
{
  __shared__ __attribute__((aligned(16))) halfT Alds[2][256*64];   // 2 x 32 KB
  __shared__ __attribute__((aligned(16))) halfT Blds[2][256*64];   // 2 x 32 KB

  int nwg = gridDim.x;
  int bid = blockIdx.x;
  int cpx = nwg >> 3;                       // nwg % 8 == 0 always here
  int swz = (bid & 7)*cpx + (bid >> 3);     // contiguous chunk per XCD
  int bpk  = nwg / nks;
  int ks   = swz / bpk;
  int rem  = swz % bpk;
  int b    = rem / (NT*MT);
  int rem2 = rem % (NT*MT);
  int nt   = rem2 / MT;
  int mt   = rem2 % MT;

  int tid = threadIdx.x;
  int w = tid >> 6, lane = tid & 63, lg = lane >> 4, li = lane & 15;
  int wm = w >> 2, wn = w & 3;
  int rA = tid >> 3;              // staging row base (0..63), +64 per j
  int cA = (tid & 7)*8;           // staging col (halfs)

  const halfT* Ab = Aall + b*sAb + (size_t)mt*256*K_ld + (size_t)ks*K_len;
  const halfT* Bb = Ball + b*sBb + (size_t)nt*256*K_ld + (size_t)ks*K_len;

  f32x4 acc[8][4];
  #pragma unroll
  for (int i=0;i<8;++i)
    #pragma unroll
    for (int j=0;j<4;++j) acc[i][j] = (f32x4){0.f,0.f,0.f,0.f};

#define STAGE(nb_, kt_)                                                        \
  do {                                                                         \
    const halfT* a0 = Ab + (size_t)(kt_)*64 + cA;                              \
    const halfT* b0 = Bb + (size_t)(kt_)*64 + cA;                              \
    _Pragma("unroll")                                                          \
    for (int j = 0; j < 4; ++j) {                                              \
      int r = rA + j*64;                                                       \
      gload_lds16(a0 + (size_t)r*K_ld, &Alds[nb_][(tid + j*512)*8]);           \
      gload_lds16(b0 + (size_t)r*K_ld, &Blds[nb_][(tid + j*512)*8]);           \
    }                                                                          \
  } while (0)

  int nk = K_len >> 6;
  int nb = 0;
  STAGE(0, 0);
  __syncthreads();                         // prologue drain (vmcnt0 + barrier)

  for (int kt = 0; kt < nk; ++kt) {
    if (kt + 1 < nk) STAGE(nb ^ 1, kt + 1);   // prefetch next K-tile first
    #pragma unroll
    for (int ksub = 0; ksub < 2; ++ksub) {
      half8 Af[8], Bf[4];
      #pragma unroll
      for (int mf = 0; mf < 8; ++mf)
        Af[mf] = *(const half8*)&Alds[nb][(wm*128 + mf*16 + li)*64 + ksub*32 + lg*8];
      #pragma unroll
      for (int nf = 0; nf < 4; ++nf)
        Bf[nf] = *(const half8*)&Blds[nb][(wn*64 + nf*16 + li)*64 + ksub*32 + lg*8];
      #pragma unroll
      for (int mf = 0; mf < 8; ++mf)
        #pragma unroll
        for (int nf = 0; nf < 4; ++nf)
          acc[mf][nf] = __builtin_amdgcn_mfma_f32_16x16x32_f16(Af[mf], Bf[nf], acc[mf][nf], 0,0,0);
    }
    __syncthreads();                       // drains prefetch (vmcnt0) + lds reads
    nb ^= 1;
  }
#undef STAGE

  // epilogue: row = mt*256 + wm*128 + mf*16 + lg*4 + r ; col = nt*256 + wn*64 + nf*16 + li
  float* Cb = Call + (size_t)ks*sKs + b*sCb;
  int colbase = nt*256 + wn*64;
  #pragma unroll
  for (int mf = 0; mf < 8; ++mf) {
    #pragma unroll
    for (int r = 0; r < 4; ++r) {
      int row = mt*256 + wm*128 + mf*16 + lg*4 + r;
      #pragma unroll
      for (int nf = 0; nf < 4; ++nf)
        Cb[(size_t)row*ldC + colbase + nf*16 + li] = acc[mf][nf][r];
    }
  }
}

// ---------------- row softmax: P16 = exp(S - max), invl = 1/sum ----------------
__global__ __launch_bounds__(256)
void softmax_rows(const float* __restrict__ S, halfT* __restrict__ P,
                  float* __restrict__ invl)
{
  __shared__ float red[4];
  int row = blockIdx.x;                    // 0..4095 = b*512+m
  int tid = threadIdx.x;
  const float* src = S + (size_t)row*L_;
  f32x4 v[4];
  float mx = -3.0e38f;
  #pragma unroll
  for (int i = 0; i < 4; ++i) {
    v[i] = *(const f32x4*)&src[(size_t)(i*256 + tid)*4];
    #pragma unroll
    for (int e = 0; e < 4; ++e) mx = fmaxf(mx, v[i][e]);
  }
  #pragma unroll
  for (int off = 1; off < 64; off <<= 1) mx = fmaxf(mx, __shfl_xor(mx, off));
  int w = tid >> 6;
  if ((tid & 63) == 0) red[w] = mx;
  __syncthreads();
  mx = fmaxf(fmaxf(red[0], red[1]), fmaxf(red[2], red[3]));

  float sum = 0.f;
  halfT* dst = P + (size_t)row*L_;
  #pragma unroll
  for (int i = 0; i < 4; ++i) {
    half4_t h;
    #pragma unroll
    for (int e = 0; e < 4; ++e) {
      float ev = __expf(v[i][e] - mx);
      sum += ev;
      h[e] = (halfT)ev;
    }
    *(half4_t*)&dst[(size_t)(i*256 + tid)*4] = h;
  }
  #pragma unroll
  for (int off = 1; off < 64; off <<= 1) sum += __shfl_xor(sum, off);
  __syncthreads();                          // protect red before reuse
  if ((tid & 63) == 0) red[w] = sum;
  __syncthreads();
  if (tid == 0) invl[row] = 1.0f / (red[0] + red[1] + red[2] + red[3]);
}

// ---------------- combine: out = invl * sum_ks rp[ks] ----------------
__global__ __launch_bounds__(256)
void combine_scale(const float* __restrict__ rp, const float* __restrict__ invl,
                   float* __restrict__ out)
{
  int bm = blockIdx.x;                     // 0..4095
  int tid = threadIdx.x;
  size_t off = (size_t)bm*D_ + tid*4;
  f32x4 v = *(const f32x4*)&rp[off];
  #pragma unroll
  for (int s = 1; s < 4; ++s)
    v += *(const f32x4*)&rp[(size_t)s*B_*M_*D_ + off];
  float sc = invl[bm];
  v *= sc;
  *(f32x4*)&out[off] = v;
}

// ---------------- fallback (tiny ws): correct, slow fp32 ----------------
__global__ void fallback_kernel(const float* __restrict__ qs,
                                const float* __restrict__ mem,
                                float* __restrict__ out)
{
  __shared__ float w_lds[4][4096];
  __shared__ float mem_s[4][1024];
  __shared__ float redb[256];
  int blk = blockIdx.x;
  int b = blk >> 7;
  int m0 = (blk & 127)*4;
  int tid = threadIdx.x;

  for (int i = tid; i < 4*1024; i += 256)
    mem_s[i>>10][i&1023] = mem[(size_t)(m0 + (i>>10))*D_ + (i&1023)];
  __syncthreads();

  float mx[4] = {-3e38f,-3e38f,-3e38f,-3e38f};
  for (int l = tid; l < L_; l += 256) {
    const float* qp = qs + ((size_t)b*L_ + l)*D_;
    float dot[4] = {0,0,0,0};
    for (int dd = 0; dd < D_; dd += 4) {
      f32x4 qv = *(const f32x4*)(qp + dd);
      #pragma unroll
      for (int mi=0; mi<4; ++mi)
        dot[mi] += qv[0]*mem_s[mi][dd] + qv[1]*mem_s[mi][dd+1]
                 + qv[2]*mem_s[mi][dd+2] + qv[3]*mem_s[mi][dd+3];
    }
    #pragma unroll
    for (int mi=0; mi<4; ++mi) { w_lds[mi][l] = dot[mi]; mx[mi] = fmaxf(mx[mi], dot[mi]); }
  }
  float Mv[4], Zv[4];
  for (int mi=0; mi<4; ++mi) {
    redb[tid] = mx[mi]; __syncthreads();
    for (int s=128; s>0; s>>=1) { if (tid<s) redb[tid]=fmaxf(redb[tid],redb[tid+s]); __syncthreads(); }
    Mv[mi] = redb[0]; __syncthreads();
  }
  float sm[4] = {0,0,0,0};
  for (int l = tid; l < L_; l += 256)
    #pragma unroll
    for (int mi=0; mi<4; ++mi) {
      float wv = __expf(w_lds[mi][l] - Mv[mi]);
      w_lds[mi][l] = wv; sm[mi] += wv;
    }
  for (int mi=0; mi<4; ++mi) {
    redb[tid] = sm[mi]; __syncthreads();
    for (int s=128; s>0; s>>=1) { if (tid<s) redb[tid]+=redb[tid+s]; __syncthreads(); }
    Zv[mi] = redb[0]; __syncthreads();
  }
  int d0 = tid*4;
  f32x4 a[4];
  #pragma unroll
  for (int mi=0;mi<4;++mi) a[mi] = (f32x4){0,0,0,0};
  for (int l = 0; l < L_; ++l) {
    f32x4 qv = *(const f32x4*)(qs + ((size_t)b*L_ + l)*D_ + d0);
    #pragma unroll
    for (int mi=0; mi<4; ++mi) a[mi] += qv * w_lds[mi][l];
  }
  #pragma unroll
  for (int mi=0; mi<4; ++mi) {
    float invz = 1.f/Zv[mi];
    #pragma unroll
    for (int c=0; c<4; ++c)
      out[((size_t)b*M_ + m0 + mi)*D_ + d0 + c] = a[mi][c]*invz;
  }
}

extern "C" void kernel_launch(void* const* d_in, const int* in_sizes, int n_in,
                              void* d_out, int out_size, void* d_ws, size_t ws_size,
                              hipStream_t stream) {
  const float* qs  = (const float*)d_in[0];
  const float* mem = (const float*)d_in[1];
  float* out = (float*)d_out;

  // tuple output: r [8*512*1024] then memory [512*1024]
  hipMemcpyAsync(out + (size_t)B_*M_*D_, mem, (size_t)M_*D_*sizeof(float),
                 hipMemcpyDeviceToDevice, stream);

  if (ws_size >= (size_t)WS_NEED) {
    char* base = (char*)d_ws;
    halfT* qsT   = (halfT*)(base + OFF_QST);
    halfT* qs16  = (halfT*)(base + OFF_QS16);
    halfT* mem16 = (halfT*)(base + OFF_MEM16);
    float* S     = (float*)(base + OFF_S);
    float* invl  = (float*)(base + OFF_INVL);
    halfT* P16   = (halfT*)(base + OFF_P16);   // overlays qs16
    float* rp    = (float*)(base + OFF_RP);    // overlays S

    prep_mem16<<<2048, 256, 0, stream>>>(mem, mem16);
    prep_qs<<<dim3(16,16,8), 256, 0, stream>>>(qs, qs16, qsT);
    // S = mem16 @ qs16^T : per b M=512, N=4096, K=1024 ; MT=2, NT=16
    gemm_bt<<<256, 512, 0, stream>>>(mem16, qs16, S,
                                     1024, 1024, 1, 16, 2, 4096,
                                     (size_t)0, (size_t)L_*D_, (size_t)M_*L_, (size_t)0);
    softmax_rows<<<4096, 256, 0, stream>>>(S, P16, invl);
    // rp[ks] = P16 @ qsT^T : per b M=512, N=1024, Kchunk=1024, nks=4 ; MT=2, NT=4
    gemm_bt<<<256, 512, 0, stream>>>(P16, qsT, rp,
                                     4096, 1024, 4, 4, 2, 1024,
                                     (size_t)M_*L_, (size_t)D_*L_, (size_t)M_*D_,
                                     (size_t)B_*M_*D_);
    combine_scale<<<4096, 256, 0, stream>>>(rp, invl, out);
  } else {
    fallback_kernel<<<1024, 256, 0, stream>>>(qs, mem, out);
  }
}

// Round 8
// 183.174 us; speedup vs baseline: 2.4454x; 1.0367x over previous
//
#include <hip/hip_runtime.h>
#include <hip/hip_fp16.h>

// Memory_Attention: r = softmax_L(memory @ qs^T) @ qs ; out = (r, memory)
// B=8 L=4096 D=1024 M=512, fp32 in/out.
//
// Round 8: DELETE prep_qs (was 78us, stuck at 2.6 TB/s across 4 variants).
// Both GEMMs consume fp32 qs directly, converting in the staging phase:
//   gemm_qk: S = mem16 @ qs^T. A=mem16 gload_lds; B=qs fp32 reg-staged
//            (8x dwordx4 -> cvt -> 4x ds_write_b128, XOR-chunk swizzle).
//   gemm_pv: rp[ks] = P16 @ qs (split-K x4). A=P16 gload_lds; B=qs fp32
//            reg-staged TRANSPOSE (32 scalar ds_write_u16, XOR swizzle) --
//            replaces the old qsT HBM round-trip with in-LDS transposes
//            overlapped under MFMA (T14 split: load early, write late).
// Both: 256x256 tile, BK=64, 8 waves, 2-phase dbuf, 1 barrier/K-step.
// LDS [n][64k] with chunk pos = (k>>3) ^ SWZ(n); frag reads use same XOR.
// Pipeline: prep_mem16 -> gemm_qk -> softmax -> gemm_pv -> combine_scale.

#define B_ 8
#define L_ 4096
#define D_ 1024
#define M_ 512

typedef _Float16 halfT;
typedef _Float16 half8 __attribute__((ext_vector_type(8)));
typedef _Float16 half4_t __attribute__((ext_vector_type(4)));
typedef float f32x4 __attribute__((ext_vector_type(4)));

// ---- ws layout (bytes) ----
#define OFF_MEM16 0ull
#define SZ_MEM16  (512ull*1024*2)             //  1,048,576
#define OFF_S     (OFF_MEM16 + SZ_MEM16)
#define SZ_S      (8ull*512*4096*4)           // 67,108,864
#define OFF_P16   (OFF_S + SZ_S)
#define SZ_P16    (8ull*512*4096*2)           // 33,554,432
#define OFF_INVL  (OFF_P16 + SZ_P16)
#define SZ_INVL   (8ull*512*4)
#define WS_NEED   (OFF_INVL + SZ_INVL)        // ~101.7 MB (ws known >= 202 MB)
#define OFF_RP    OFF_S                       // overlay: S dead after softmax

#define SWZ(n) ((((n)&7) ^ (((n)>>5)&7)))

__device__ __forceinline__ void gload_lds16(const halfT* g, halfT* l) {
  __builtin_amdgcn_global_load_lds(
      (const __attribute__((address_space(1))) unsigned int*)(const void*)g,
      (__attribute__((address_space(3))) unsigned int*)l, 16, 0, 0);
}

// ---------------- prep ----------------
__global__ void prep_mem16(const float* __restrict__ mem, halfT* __restrict__ mem16) {
  int i = blockIdx.x*256 + threadIdx.x;   // 2048*256 = 524288 exact
  mem16[i] = (halfT)mem[i];
}

// Shared MFMA inner phase: 8x4 frags, A linear, B XOR-chunked.
#define GEMM_COMPUTE(AT_, BT_)                                                 \
    _Pragma("unroll")                                                          \
    for (int ksub = 0; ksub < 2; ++ksub) {                                     \
      half8 Af[8], Bf[4];                                                      \
      _Pragma("unroll")                                                        \
      for (int mf = 0; mf < 8; ++mf)                                           \
        Af[mf] = *(const half8*)&(AT_)[(wm*128 + mf*16 + li)*64 + ksub*32 + lg*8]; \
      _Pragma("unroll")                                                        \
      for (int nf = 0; nf < 4; ++nf) {                                         \
        int n_ = wn*64 + nf*16 + li;                                           \
        Bf[nf] = *(const half8*)&(BT_)[n_*64 + (((ksub*4 + lg) ^ SWZ(n_)) << 3)]; \
      }                                                                        \
      _Pragma("unroll")                                                        \
      for (int mf = 0; mf < 8; ++mf)                                           \
        _Pragma("unroll")                                                      \
        for (int nf = 0; nf < 4; ++nf)                                         \
          acc[mf][nf] = __builtin_amdgcn_mfma_f32_16x16x32_f16(Af[mf], Bf[nf], acc[mf][nf], 0,0,0); \
    }

// ---------------- gemm_qk: S[b][512][4096] = mem16 @ qs^T ----------------
// Per b: M=512 (MT=2), N=4096 (NT=16), K=1024. B-row n = qs row l=n (k=d).
__global__ __launch_bounds__(512, 2)
void gemm_qk(const halfT* __restrict__ mem16, const float* __restrict__ qs,
             float* __restrict__ S)
{
  __shared__ __attribute__((aligned(16))) halfT At[2][256*64];   // 64 KB
  __shared__ __attribute__((aligned(16))) halfT Bt[2][256*64];   // 64 KB

  int bid = blockIdx.x;                      // 256
  int swz = (bid & 7)*32 + (bid >> 3);       // XCD-contiguous
  int b   = swz >> 5;                        // one b per XCD
  int rem = swz & 31;
  int nt  = rem >> 1;
  int mt  = rem & 1;

  int tid = threadIdx.x;
  int w = tid >> 6, lane = tid & 63, lg = lane >> 4, li = lane & 15;
  int wm = w >> 2, wn = w & 3;

  const halfT* Ab = mem16 + (size_t)mt*256*1024;
  const float* Bb = qs + ((size_t)b*L_ + nt*256)*D_;
  int nrow  = tid >> 1;
  int bhalf = tid & 1;
  int swr   = SWZ(nrow);

  f32x4 acc[8][4];
  #pragma unroll
  for (int i=0;i<8;++i)
    #pragma unroll
    for (int j=0;j<4;++j) acc[i][j] = (f32x4){0.f,0.f,0.f,0.f};

  f32x4 bx[8];

#define GLOADB_QK(kt_)                                                         \
  do {                                                                         \
    const float* src = Bb + (size_t)nrow*D_ + (kt_)*64 + bhalf*32;             \
    _Pragma("unroll")                                                          \
    for (int j = 0; j < 8; ++j) bx[j] = *(const f32x4*)(src + j*4);            \
  } while (0)

#define STAGEA_QK(nb_, kt_)                                                    \
  do {                                                                         \
    const halfT* a0 = Ab + (size_t)(kt_)*64 + (tid & 7)*8;                     \
    _Pragma("unroll")                                                          \
    for (int j = 0; j < 4; ++j)                                                \
      gload_lds16(a0 + (size_t)((tid >> 3) + j*64)*1024, &At[nb_][(tid + j*512)*8]); \
  } while (0)

#define CVTWRITE_QK(nb_)                                                       \
  do {                                                                         \
    _Pragma("unroll")                                                          \
    for (int cj = 0; cj < 4; ++cj) {                                           \
      half8 h;                                                                 \
      _Pragma("unroll")                                                        \
      for (int e = 0; e < 4; ++e) { h[e] = (halfT)bx[cj*2][e]; h[4+e] = (halfT)bx[cj*2+1][e]; } \
      int pos = (bhalf*4 + cj) ^ swr;                                          \
      *(half8*)&Bt[nb_][nrow*64 + pos*8] = h;                                  \
    }                                                                          \
  } while (0)

  GLOADB_QK(0);
  STAGEA_QK(0, 0);
  CVTWRITE_QK(0);
  __syncthreads();                           // implicit vmcnt(0): tile 0 ready

  int nb = 0;
  for (int kt = 0; kt < 16; ++kt) {
    if (kt + 1 < 16) { GLOADB_QK(kt + 1); STAGEA_QK(nb ^ 1, kt + 1); }
    GEMM_COMPUTE(At[nb], Bt[nb]);
    if (kt + 1 < 16) CVTWRITE_QK(nb ^ 1);    // after compute: loads have landed
    __syncthreads();
    nb ^= 1;
  }
#undef GLOADB_QK
#undef STAGEA_QK
#undef CVTWRITE_QK

  float* Cb = S + (size_t)b*M_*L_;
  int colbase = nt*256 + wn*64;
  #pragma unroll
  for (int mf = 0; mf < 8; ++mf) {
    #pragma unroll
    for (int r = 0; r < 4; ++r) {
      int row = mt*256 + wm*128 + mf*16 + lg*4 + r;
      #pragma unroll
      for (int nf = 0; nf < 4; ++nf)
        Cb[(size_t)row*L_ + colbase + nf*16 + li] = acc[mf][nf][r];
    }
  }
}

// ---------------- gemm_pv: rp[ks][b][512][1024] = P16 @ qs (K-chunk ks) ----------------
// Per (b,ks): M=512 (MT=2), N=1024 (NT=4), Kchunk=1024. B = qs[k=l][n=d]:
// staged with in-LDS transpose into [n][64k] (32 scalar swizzled ds_write_u16).
__global__ __launch_bounds__(512, 2)
void gemm_pv(const halfT* __restrict__ P16, const float* __restrict__ qs,
             float* __restrict__ rp)
{
  __shared__ __attribute__((aligned(16))) halfT At[2][256*64];   // 64 KB
  __shared__ __attribute__((aligned(16))) halfT Bt[2][256*64];   // 64 KB

  int bid = blockIdx.x;                      // 256
  int swz = (bid & 7)*32 + (bid >> 3);
  int ks  = swz >> 6;                        // 0..3
  int rem = swz & 63;
  int b   = rem >> 3;
  int nt  = (rem >> 1) & 3;
  int mt  = rem & 1;

  int tid = threadIdx.x;
  int w = tid >> 6, lane = tid & 63, lg = lane >> 4, li = lane & 15;
  int wm = w >> 2, wn = w & 3;

  const halfT* Ab = P16 + (size_t)b*M_*L_ + (size_t)mt*256*L_ + ks*1024;
  const float* Bb = qs + ((size_t)b*L_ + ks*1024)*D_ + nt*256;
  int krow = tid >> 3;                       // 0..63 (krow>>3 == wave)
  int seg  = tid & 7;

  f32x4 acc[8][4];
  #pragma unroll
  for (int i=0;i<8;++i)
    #pragma unroll
    for (int j=0;j<4;++j) acc[i][j] = (f32x4){0.f,0.f,0.f,0.f};

  f32x4 bx[8];

#define GLOADB_PV(kt_)                                                         \
  do {                                                                         \
    const float* src = Bb + (size_t)((kt_)*64 + krow)*D_ + seg*32;             \
    _Pragma("unroll")                                                          \
    for (int j = 0; j < 8; ++j) bx[j] = *(const f32x4*)(src + j*4);            \
  } while (0)

#define STAGEA_PV(nb_, kt_)                                                    \
  do {                                                                         \
    const halfT* a0 = Ab + (size_t)(kt_)*64 + (tid & 7)*8;                     \
    _Pragma("unroll")                                                          \
    for (int j = 0; j < 4; ++j)                                                \
      gload_lds16(a0 + (size_t)((tid >> 3) + j*64)*L_, &At[nb_][(tid + j*512)*8]); \
  } while (0)

#define CVTWRITE_PV(nb_)                                                       \
  do {                                                                         \
    _Pragma("unroll")                                                          \
    for (int i = 0; i < 32; ++i) {                                             \
      int n_ = seg*32 + i;                                                     \
      Bt[nb_][n_*64 + ((((krow >> 3) ^ SWZ(n_)) << 3)) + (krow & 7)] =         \
          (halfT)bx[i >> 2][i & 3];                                            \
    }                                                                          \
  } while (0)

  GLOADB_PV(0);
  STAGEA_PV(0, 0);
  CVTWRITE_PV(0);
  __syncthreads();

  int nb = 0;
  for (int kt = 0; kt < 16; ++kt) {
    if (kt + 1 < 16) { GLOADB_PV(kt + 1); STAGEA_PV(nb ^ 1, kt + 1); }
    GEMM_COMPUTE(At[nb], Bt[nb]);
    if (kt + 1 < 16) CVTWRITE_PV(nb ^ 1);
    __syncthreads();
    nb ^= 1;
  }
#undef GLOADB_PV
#undef STAGEA_PV
#undef CVTWRITE_PV

  float* Cb = rp + (size_t)ks*((size_t)B_*M_*D_) + (size_t)b*M_*D_;
  int colbase = nt*256 + wn*64;
  #pragma unroll
  for (int mf = 0; mf < 8; ++mf) {
    #pragma unroll
    for (int r = 0; r < 4; ++r) {
      int row = mt*256 + wm*128 + mf*16 + lg*4 + r;
      #pragma unroll
      for (int nf = 0; nf < 4; ++nf)
        Cb[(size_t)row*D_ + colbase + nf*16 + li] = acc[mf][nf][r];
    }
  }
}

// ---------------- row softmax: P16 = exp(S - max), invl = 1/sum ----------------
__global__ __launch_bounds__(256)
void softmax_rows(const float* __restrict__ S, halfT* __restrict__ P,
                  float* __restrict__ invl)
{
  __shared__ float red[4];
  int row = blockIdx.x;                    // 0..4095 = b*512+m
  int tid = threadIdx.x;
  const float* src = S + (size_t)row*L_;
  f32x4 v[4];
  float mx = -3.0e38f;
  #pragma unroll
  for (int i = 0; i < 4; ++i) {
    v[i] = *(const f32x4*)&src[(size_t)(i*256 + tid)*4];
    #pragma unroll
    for (int e = 0; e < 4; ++e) mx = fmaxf(mx, v[i][e]);
  }
  #pragma unroll
  for (int off = 1; off < 64; off <<= 1) mx = fmaxf(mx, __shfl_xor(mx, off));
  int w = tid >> 6;
  if ((tid & 63) == 0) red[w] = mx;
  __syncthreads();
  mx = fmaxf(fmaxf(red[0], red[1]), fmaxf(red[2], red[3]));

  float sum = 0.f;
  halfT* dst = P + (size_t)row*L_;
  #pragma unroll
  for (int i = 0; i < 4; ++i) {
    half4_t h;
    #pragma unroll
    for (int e = 0; e < 4; ++e) {
      float ev = __expf(v[i][e] - mx);
      sum += ev;
      h[e] = (halfT)ev;
    }
    *(half4_t*)&dst[(size_t)(i*256 + tid)*4] = h;
  }
  #pragma unroll
  for (int off = 1; off < 64; off <<= 1) sum += __shfl_xor(sum, off);
  __syncthreads();
  if ((tid & 63) == 0) red[w] = sum;
  __syncthreads();
  if (tid == 0) invl[row] = 1.0f / (red[0] + red[1] + red[2] + red[3]);
}

// ---------------- combine: out = invl * sum_ks rp[ks] ----------------
__global__ __launch_bounds__(256)
void combine_scale(const float* __restrict__ rp, const float* __restrict__ invl,
                   float* __restrict__ out)
{
  int bm = blockIdx.x;                     // 0..4095
  int tid = threadIdx.x;
  size_t off = (size_t)bm*D_ + tid*4;
  f32x4 v = *(const f32x4*)&rp[off];
  #pragma unroll
  for (int s = 1; s < 4; ++s)
    v += *(const f32x4*)&rp[(size_t)s*B_*M_*D_ + off];
  float sc = invl[bm];
  v *= sc;
  *(f32x4*)&out[off] = v;
}

// ---------------- fallback (tiny ws): correct, slow fp32 ----------------
__global__ void fallback_kernel(const float* __restrict__ qs,
                                const float* __restrict__ mem,
                                float* __restrict__ out)
{
  __shared__ float w_lds[4][4096];
  __shared__ float mem_s[4][1024];
  __shared__ float redb[256];
  int blk = blockIdx.x;
  int b = blk >> 7;
  int m0 = (blk & 127)*4;
  int tid = threadIdx.x;

  for (int i = tid; i < 4*1024; i += 256)
    mem_s[i>>10][i&1023] = mem[(size_t)(m0 + (i>>10))*D_ + (i&1023)];
  __syncthreads();

  float mx[4] = {-3e38f,-3e38f,-3e38f,-3e38f};
  for (int l = tid; l < L_; l += 256) {
    const float* qp = qs + ((size_t)b*L_ + l)*D_;
    float dot[4] = {0,0,0,0};
    for (int dd = 0; dd < D_; dd += 4) {
      f32x4 qv = *(const f32x4*)(qp + dd);
      #pragma unroll
      for (int mi=0; mi<4; ++mi)
        dot[mi] += qv[0]*mem_s[mi][dd] + qv[1]*mem_s[mi][dd+1]
                 + qv[2]*mem_s[mi][dd+2] + qv[3]*mem_s[mi][dd+3];
    }
    #pragma unroll
    for (int mi=0; mi<4; ++mi) { w_lds[mi][l] = dot[mi]; mx[mi] = fmaxf(mx[mi], dot[mi]); }
  }
  float Mv[4], Zv[4];
  for (int mi=0; mi<4; ++mi) {
    redb[tid] = mx[mi]; __syncthreads();
    for (int s=128; s>0; s>>=1) { if (tid<s) redb[tid]=fmaxf(redb[tid],redb[tid+s]); __syncthreads(); }
    Mv[mi] = redb[0]; __syncthreads();
  }
  float sm[4] = {0,0,0,0};
  for (int l = tid; l < L_; l += 256)
    #pragma unroll
    for (int mi=0; mi<4; ++mi) {
      float wv = __expf(w_lds[mi][l] - Mv[mi]);
      w_lds[mi][l] = wv; sm[mi] += wv;
    }
  for (int mi=0; mi<4; ++mi) {
    redb[tid] = sm[mi]; __syncthreads();
    for (int s=128; s>0; s>>=1) { if (tid<s) redb[tid]+=redb[tid+s]; __syncthreads(); }
    Zv[mi] = redb[0]; __syncthreads();
  }
  int d0 = tid*4;
  f32x4 a[4];
  #pragma unroll
  for (int mi=0;mi<4;++mi) a[mi] = (f32x4){0,0,0,0};
  for (int l = 0; l < L_; ++l) {
    f32x4 qv = *(const f32x4*)(qs + ((size_t)b*L_ + l)*D_ + d0);
    #pragma unroll
    for (int mi=0; mi<4; ++mi) a[mi] += qv * w_lds[mi][l];
  }
  #pragma unroll
  for (int mi=0; mi<4; ++mi) {
    float invz = 1.f/Zv[mi];
    #pragma unroll
    for (int c=0; c<4; ++c)
      out[((size_t)b*M_ + m0 + mi)*D_ + d0 + c] = a[mi][c]*invz;
  }
}

extern "C" void kernel_launch(void* const* d_in, const int* in_sizes, int n_in,
                              void* d_out, int out_size, void* d_ws, size_t ws_size,
                              hipStream_t stream) {
  const float* qs  = (const float*)d_in[0];
  const float* mem = (const float*)d_in[1];
  float* out = (float*)d_out;

  // tuple output: r [8*512*1024] then memory [512*1024]
  hipMemcpyAsync(out + (size_t)B_*M_*D_, mem, (size_t)M_*D_*sizeof(float),
                 hipMemcpyDeviceToDevice, stream);

  if (ws_size >= (size_t)WS_NEED) {
    char* base = (char*)d_ws;
    halfT* mem16 = (halfT*)(base + OFF_MEM16);
    float* S     = (float*)(base + OFF_S);
    halfT* P16   = (halfT*)(base + OFF_P16);
    float* invl  = (float*)(base + OFF_INVL);
    float* rp    = (float*)(base + OFF_RP);    // overlays S (dead after softmax)

    prep_mem16<<<2048, 256, 0, stream>>>(mem, mem16);
    gemm_qk<<<256, 512, 0, stream>>>(mem16, qs, S);
    softmax_rows<<<4096, 256, 0, stream>>>(S, P16, invl);
    gemm_pv<<<256, 512, 0, stream>>>(P16, qs, rp);
    combine_scale<<<4096, 256, 0, stream>>>(rp, invl, out);
  } else {
    fallback_kernel<<<1024, 256, 0, stream>>>(qs, mem, out);
  }
}